// Round 7
// baseline (1778.593 us; speedup 1.0000x reference)
//
#include <hip/hip_runtime.h>
#include <hip/hip_bf16.h>
#include <cmath>

// Problem constants
#define BB 64
#define NN 512
#define NBS 8
#define EE 2048
#define HH 128
#define LL 3
#define KK 4
#define AF 82
#define BF 6
#define SLAB 4194304   // B*N*H floats

typedef __attribute__((ext_vector_type(8))) short bf16x8;
typedef __attribute__((ext_vector_type(4))) float f32x4;

__device__ __forceinline__ float gelu1(float x){ return 0.5f*x*(1.f+erff(x*0.7071067811865475f)); }
__device__ __forceinline__ float sig1(float x){ return 1.f/(1.f+expf(-x)); }
__device__ __forceinline__ short f2bs(float x){ __hip_bfloat16 b=__float2bfloat16(x); return *reinterpret_cast<short*>(&b); }
__device__ __forceinline__ float bs2f(short s){ unsigned u = ((unsigned)(unsigned short)s) << 16; union{unsigned u; float f;} c; c.u=u; return c.f; }
__device__ __forceinline__ void split2(float v, short& hi, short& lo){ hi = f2bs(v); lo = f2bs(v - bs2f(hi)); }

#define MFMA3(ACC, AH, AL, BH, BL) \
    ACC = __builtin_amdgcn_mfma_f32_16x16x32_bf16(AH, BH, ACC, 0,0,0); \
    ACC = __builtin_amdgcn_mfma_f32_16x16x32_bf16(AL, BH, ACC, 0,0,0); \
    ACC = __builtin_amdgcn_mfma_f32_16x16x32_bf16(AH, BL, ACC, 0,0,0);

// ---------------------------------------------------------------------------
// vchain (col-split): u2 -> support -> fu -> sv -> wzm1 z-gate -> GRU.
// Block = 256 thr = 4 waves, 16 rows; wave owns 32 cols. Grid = B*N/16 = 2048.
// Intermediates in LDS as hi/lo bf16 planes (split once at producer).
// ---------------------------------------------------------------------------
__global__ __launch_bounds__(256) void vchain(
    const short* __restrict__ nlh, const short* __restrict__ nll,
    float* __restrict__ vf, short* __restrict__ vfh, short* __restrict__ vfl,
    const float* __restrict__ h0,
    const short* __restrict__ wu2, const float* __restrict__ u2b,
    const short* __restrict__ wfu, const float* __restrict__ fub,
    const short* __restrict__ wzm, const float* __restrict__ zmb,
    const short* __restrict__ wih, const short* __restrict__ whh,
    const float* __restrict__ bih, const float* __restrict__ bhh,
    const float* __restrict__ t2, const float* __restrict__ m2m,
    float theta)
{
    __shared__ __align__(16) short sh[16*136];
    __shared__ __align__(16) short sl[16*136];
    const int t = threadIdx.x;
    const int lane = t & 63, wv = t >> 6;
    const int quad = lane >> 4, ml = lane & 15;
    const int base = blockIdx.x * 16;
    const int arow = base + ml;
    const int bb = base >> 9;
    const int c0 = wv*32 + ml;          // wave owns cols c0 and c0+16
    const int kq0 = quad*8;

    f32x4 acc0 = (f32x4){0.f,0.f,0.f,0.f}, acc1 = (f32x4){0.f,0.f,0.f,0.f};

    // ---- stage A: hi = concat(nl, vf) @ u2, K=256
    #pragma unroll
    for (int kc = 0; kc < 8; ++kc) {
        const int kq = kc*32 + kq0;
        bf16x8 ah, al;
        if (kc < 4) {
            ah = *(const bf16x8*)(nlh + (size_t)arow*128 + kq);
            al = *(const bf16x8*)(nll + (size_t)arow*128 + kq);
        } else {
            ah = *(const bf16x8*)(vfh + (size_t)arow*128 + kq - 128);
            al = *(const bf16x8*)(vfl + (size_t)arow*128 + kq - 128);
        }
        const short* bp0 = wu2 + (size_t)c0*256 + kq;
        const short* bp1 = wu2 + (size_t)(c0+16)*256 + kq;
        MFMA3(acc0, ah, al, *(const bf16x8*)bp0, *(const bf16x8*)(bp0+98304));
        MFMA3(acc1, ah, al, *(const bf16x8*)bp1, *(const bf16x8*)(bp1+98304));
    }
    f32x4 sup0, sup1;
    {
        float bj0 = u2b[c0], bj1 = u2b[c0+16];
        #pragma unroll
        for (int r = 0; r < 4; ++r) {
            int row = base + quad*4 + r;
            sup0[r] = 0.9f*(acc0[r] + bj0) + 0.1f*h0[(size_t)row*128 + c0];
            sup1[r] = 0.9f*(acc1[r] + bj1) + 0.1f*h0[(size_t)row*128 + c0+16];
        }
    }
    #pragma unroll
    for (int r = 0; r < 4; ++r) {
        int lrow = quad*4 + r;
        short h_, l_;
        split2(sup0[r], h_, l_); sh[lrow*136 + c0] = h_; sl[lrow*136 + c0] = l_;
        split2(sup1[r], h_, l_); sh[lrow*136 + c0+16] = h_; sl[lrow*136 + c0+16] = l_;
    }
    __syncthreads();

    // ---- stage B: sv = theta*(sup@fu + b) + (1-theta)*sup
    acc0 = (f32x4){0.f,0.f,0.f,0.f}; acc1 = (f32x4){0.f,0.f,0.f,0.f};
    #pragma unroll
    for (int kc = 0; kc < 4; ++kc) {
        const int kq = kc*32 + kq0;
        bf16x8 xh = *(const bf16x8*)&sh[ml*136 + kq];
        bf16x8 xl = *(const bf16x8*)&sl[ml*136 + kq];
        const short* bp0 = wfu + (size_t)c0*128 + kq;
        const short* bp1 = wfu + (size_t)(c0+16)*128 + kq;
        MFMA3(acc0, xh, xl, *(const bf16x8*)bp0, *(const bf16x8*)(bp0+49152));
        MFMA3(acc1, xh, xl, *(const bf16x8*)bp1, *(const bf16x8*)(bp1+49152));
    }
    f32x4 sv0, sv1;
    {
        float bj0 = fub[c0], bj1 = fub[c0+16];
        #pragma unroll
        for (int r = 0; r < 4; ++r) {
            sv0[r] = theta*(acc0[r] + bj0) + (1.f-theta)*sup0[r];
            sv1[r] = theta*(acc1[r] + bj1) + (1.f-theta)*sup1[r];
        }
    }
    __syncthreads();
    #pragma unroll
    for (int r = 0; r < 4; ++r) {
        int lrow = quad*4 + r;
        short h_, l_;
        split2(sv0[r], h_, l_); sh[lrow*136 + c0] = h_; sl[lrow*136 + c0] = l_;
        split2(sv1[r], h_, l_); sh[lrow*136 + c0+16] = h_; sl[lrow*136 + c0+16] = l_;
    }
    __syncthreads();

    // ---- stage C: z = sig(sv@wzm1 + b + t2[b]); hid = (1-z)*sv + z*m2m[b]
    acc0 = (f32x4){0.f,0.f,0.f,0.f}; acc1 = (f32x4){0.f,0.f,0.f,0.f};
    #pragma unroll
    for (int kc = 0; kc < 4; ++kc) {
        const int kq = kc*32 + kq0;
        bf16x8 xh = *(const bf16x8*)&sh[ml*136 + kq];
        bf16x8 xl = *(const bf16x8*)&sl[ml*136 + kq];
        const short* bp0 = wzm + (size_t)c0*128 + kq;
        const short* bp1 = wzm + (size_t)(c0+16)*128 + kq;
        MFMA3(acc0, xh, xl, *(const bf16x8*)bp0, *(const bf16x8*)(bp0+49152));
        MFMA3(acc1, xh, xl, *(const bf16x8*)bp1, *(const bf16x8*)(bp1+49152));
    }
    f32x4 hid0, hid1;
    {
        float bj0 = zmb[c0], bj1 = zmb[c0+16];
        float t20 = t2[(size_t)bb*128 + c0], t21 = t2[(size_t)bb*128 + c0+16];
        float m20 = m2m[(size_t)bb*128 + c0], m21 = m2m[(size_t)bb*128 + c0+16];
        #pragma unroll
        for (int r = 0; r < 4; ++r) {
            float z0 = sig1(acc0[r] + bj0 + t20);
            float z1 = sig1(acc1[r] + bj1 + t21);
            hid0[r] = (1.f-z0)*sv0[r] + z0*m20;
            hid1[r] = (1.f-z1)*sv1[r] + z1*m21;
        }
    }
    __syncthreads();
    #pragma unroll
    for (int r = 0; r < 4; ++r) {
        int lrow = quad*4 + r;
        short h_, l_;
        split2(hid0[r], h_, l_); sh[lrow*136 + c0] = h_; sl[lrow*136 + c0] = l_;
        split2(hid1[r], h_, l_); sh[lrow*136 + c0+16] = h_; sl[lrow*136 + c0+16] = l_;
    }
    __syncthreads();

    // ---- stage D: GRU
    bf16x8 xfh[4], xfl[4];
    #pragma unroll
    for (int kc = 0; kc < 4; ++kc) {
        const int kq = kc*32 + kq0;
        xfh[kc] = *(const bf16x8*)&sh[ml*136 + kq];
        xfl[kc] = *(const bf16x8*)&sl[ml*136 + kq];
    }
    f32x4 rg0, rg1, zg0, zg1;
    #pragma unroll
    for (int g = 0; g < 3; ++g) {
        f32x4 gi0 = (f32x4){0.f,0.f,0.f,0.f}, gi1 = (f32x4){0.f,0.f,0.f,0.f};
        f32x4 gh0 = (f32x4){0.f,0.f,0.f,0.f}, gh1 = (f32x4){0.f,0.f,0.f,0.f};
        #pragma unroll
        for (int kc = 0; kc < 4; ++kc) {
            const int kq = kc*32 + kq0;
            bf16x8 vh = *(const bf16x8*)(vfh + (size_t)arow*128 + kq);
            bf16x8 vl = *(const bf16x8*)(vfl + (size_t)arow*128 + kq);
            const size_t w0 = (size_t)(g*128 + c0)*128 + kq;
            const size_t w1 = (size_t)(g*128 + c0+16)*128 + kq;
            MFMA3(gi0, xfh[kc], xfl[kc], *(const bf16x8*)(wih+w0), *(const bf16x8*)(wih+w0+49152));
            MFMA3(gi1, xfh[kc], xfl[kc], *(const bf16x8*)(wih+w1), *(const bf16x8*)(wih+w1+49152));
            MFMA3(gh0, vh, vl, *(const bf16x8*)(whh+w0), *(const bf16x8*)(whh+w0+49152));
            MFMA3(gh1, vh, vl, *(const bf16x8*)(whh+w1), *(const bf16x8*)(whh+w1+49152));
        }
        if (g == 0) {
            float b10 = bih[c0], b20 = bhh[c0], b11 = bih[c0+16], b21 = bhh[c0+16];
            #pragma unroll
            for (int r = 0; r < 4; ++r) {
                rg0[r] = sig1(gi0[r] + b10 + gh0[r] + b20);
                rg1[r] = sig1(gi1[r] + b11 + gh1[r] + b21);
            }
        } else if (g == 1) {
            float b10 = bih[128+c0], b20 = bhh[128+c0], b11 = bih[128+c0+16], b21 = bhh[128+c0+16];
            #pragma unroll
            for (int r = 0; r < 4; ++r) {
                zg0[r] = sig1(gi0[r] + b10 + gh0[r] + b20);
                zg1[r] = sig1(gi1[r] + b11 + gh1[r] + b21);
            }
        } else {
            float b10 = bih[256+c0], b20 = bhh[256+c0], b11 = bih[256+c0+16], b21 = bhh[256+c0+16];
            #pragma unroll
            for (int r = 0; r < 4; ++r) {
                int row = base + quad*4 + r;
                size_t off0 = (size_t)row*128 + c0;
                size_t off1 = off0 + 16;
                float n0 = tanhf(gi0[r] + b10 + rg0[r]*(gh0[r] + b20));
                float n1 = tanhf(gi1[r] + b11 + rg1[r]*(gh1[r] + b21));
                float o0 = (1.f-zg0[r])*n0 + zg0[r]*vf[off0];
                float o1 = (1.f-zg1[r])*n1 + zg1[r]*vf[off1];
                vf[off0] = o0; vf[off1] = o1;
                short h_, l_;
                split2(o0, h_, l_); vfh[off0] = h_; vfl[off0] = l_;
                split2(o1, h_, l_); vfh[off1] = h_; vfl[off1] = l_;
            }
        }
    }
}

// ---------------------------------------------------------------------------
// mvscore: one head per blockIdx.z; block = 128 rows. Grid (256,1,4).
// ---------------------------------------------------------------------------
__global__ __launch_bounds__(256) void mvscore_kernel(
    const short* __restrict__ vfh, const short* __restrict__ vfl,
    const short* __restrict__ WT, const float* __restrict__ bias,
    const float* __restrict__ master,
    const float* __restrict__ wbw, const float* __restrict__ wbb,
    float* __restrict__ score)
{
    const int t = threadIdx.x;
    const int lane = t & 63, wv = t >> 6;
    const int quad = lane >> 4, ml = lane & 15;
    const int k = blockIdx.z;
    const int tile = blockIdx.x;
    const int b = tile >> 2;
    const int r0 = tile*128 + wv*32 + ml;
    const int r1 = r0 + 16;

    bf16x8 a0h[4], a0l[4], a1h[4], a1l[4];
    #pragma unroll
    for (int kc = 0; kc < 4; ++kc) {
        const int kq = kc*32 + quad*8;
        a0h[kc] = *(const bf16x8*)(vfh + (size_t)r0*128 + kq);
        a0l[kc] = *(const bf16x8*)(vfl + (size_t)r0*128 + kq);
        a1h[kc] = *(const bf16x8*)(vfh + (size_t)r1*128 + kq);
        a1l[kc] = *(const bf16x8*)(vfl + (size_t)r1*128 + kq);
    }

    f32x4 acc[16];
    #pragma unroll
    for (int i = 0; i < 16; ++i) acc[i] = (f32x4){0.f,0.f,0.f,0.f};
    const short* wcol = WT + (size_t)k*16384 + (size_t)ml*128;
    #pragma unroll
    for (int kc = 0; kc < 4; ++kc) {
        const int kq = kc*32 + quad*8;
        #pragma unroll
        for (int nt = 0; nt < 8; ++nt) {
            const short* bp = wcol + (size_t)nt*16*128 + kq;
            bf16x8 bh = *(const bf16x8*)bp;
            bf16x8 bl = *(const bf16x8*)(bp + 196608);
            MFMA3(acc[nt],   a0h[kc], a0l[kc], bh, bl);
            MFMA3(acc[8+nt], a1h[kc], a1l[kc], bh, bl);
        }
    }
    float wv8[8], bj8[8];
    #pragma unroll
    for (int nt = 0; nt < 8; ++nt) {
        int col = nt*16 + ml;
        wv8[nt] = master[(size_t)b*128 + col] * wbw[(size_t)k*128 + col];
        bj8[nt] = bias[(size_t)k*128 + col];
    }
    float kb = wbb[k];
    #pragma unroll
    for (int mt = 0; mt < 2; ++mt) {
        #pragma unroll
        for (int r = 0; r < 4; ++r) {
            float s = 0.f;
            #pragma unroll
            for (int nt = 0; nt < 8; ++nt)
                s += tanhf(acc[mt*8+nt][r] + bj8[nt]) * wv8[nt];
            s += __shfl_xor(s, 1); s += __shfl_xor(s, 2);
            s += __shfl_xor(s, 4); s += __shfl_xor(s, 8);
            if (ml == 0) {
                int nloc = (tile & 3)*128 + wv*32 + mt*16 + quad*4 + r;
                score[((size_t)(b*KK + k))*NN + nloc] = s + kb;
            }
        }
    }
}

// ---------------------------------------------------------------------------
// postatt: softmax (4 heads) + ctx + kmm + full master path + master GRU.
// grid = 64 blocks (one per batch row).
// ---------------------------------------------------------------------------
__global__ __launch_bounds__(256) void postatt(
    const float* __restrict__ score, const float* __restrict__ vm,
    const float* __restrict__ vf,
    float* __restrict__ master,
    const float* __restrict__ wmain_w, const float* __restrict__ wmain_b,
    const float* __restrict__ khead_w, const float* __restrict__ khead_b,
    const float* __restrict__ wm2m_w,  const float* __restrict__ wm2m_b,
    const float* __restrict__ wmaster_w, const float* __restrict__ wmaster_b,
    const float* __restrict__ wzm2_w,  const float* __restrict__ wzm2_b,
    const float* __restrict__ wzs1_w,  const float* __restrict__ wzs1_b,
    const float* __restrict__ wzs2_w,  const float* __restrict__ wzs2_b,
    const float* __restrict__ WTih, const float* __restrict__ WThh,
    const float* __restrict__ bih, const float* __restrict__ bhh,
    float* __restrict__ m2m_out, float* __restrict__ t2_out)
{
    __shared__ float att[4][512];
    __shared__ float cxs[4][128];
    __shared__ float satts[4];
    __shared__ float xs[512], ms[128];
    __shared__ float v_mtm[128], v_m2m[128], v_mself[128], v_t2[128];
    __shared__ float v_ts1[128], v_ts2[128], v_hsup[128];
    __shared__ float gi[384], gh2[384];
    __shared__ float red[256];
    const int t = threadIdx.x;
    const int b = blockIdx.x;

    if (t < 128) ms[t] = master[(size_t)b*128 + t];

    // softmax per head
    for (int k = 0; k < 4; ++k) {
        float v0 = score[((size_t)(b*4+k))*512 + t];
        float v1 = score[((size_t)(b*4+k))*512 + 256 + t];
        red[t] = fmaxf(v0, v1); __syncthreads();
        for (int s = 128; s; s >>= 1) { if (t < s) red[t] = fmaxf(red[t], red[t+s]); __syncthreads(); }
        float mx = red[0]; __syncthreads();
        float e0 = expf(v0 - mx) * vm[b*NN + t];
        float e1 = expf(v1 - mx) * vm[b*NN + t + 256];
        red[t] = e0 + e1; __syncthreads();
        for (int s = 128; s; s >>= 1) { if (t < s) red[t] += red[t+s]; __syncthreads(); }
        float sum = red[0];
        float inv = 1.f / (sum + 1e-6f);
        att[k][t] = e0*inv; att[k][256+t] = e1*inv;
        if (t == 0) satts[k] = sum*inv;
        __syncthreads();
    }

    // ctx[k][d] = sum_n att[k][n]*vf[b,n,d]
    {
        const int d = t & 127, kh = t >> 7;
        #pragma unroll
        for (int p = 0; p < 2; ++p) {
            int k = kh*2 + p;
            const float* V = vf + (size_t)b*NN*HH + d;
            float s = 0.f;
            #pragma unroll 8
            for (int n = 0; n < NN; ++n) s += att[k][n]*V[(size_t)n*128];
            cxs[k][d] = s;
        }
    }
    __syncthreads();

    const int c = t & 127, p = t >> 7;

    // kmm -> xs
    #pragma unroll
    for (int k = 0; k < 4; ++k) {
        const float* Wk = wmain_w + (size_t)k*16384;
        float s = 0.f;
        for (int d = p*64; d < p*64+64; ++d) s += cxs[k][d]*Wk[(size_t)d*128 + c];
        red[t] = s; __syncthreads();
        if (t < 128) xs[k*128 + c] = red[c] + red[c+128] + satts[k]*wmain_b[k*128 + c];
        __syncthreads();
    }

    auto matvec = [&](const float* src, const float* __restrict__ W,
                      const float* __restrict__ bias, int K, float* out, int act) {
        int half = K >> 1;
        int k0 = p*half, k1 = k0 + half;
        float s = 0.f;
        for (int k = k0; k < k1; ++k) s += src[k]*W[(size_t)k*128 + c];
        red[t] = s; __syncthreads();
        if (t < 128) {
            float v = red[c] + red[c+128] + bias[c];
            if (act == 1) v = gelu1(v); else if (act == 2) v = tanhf(v);
            out[c] = v;
        }
        __syncthreads();
    };

    matvec(xs, khead_w, khead_b, 512, v_mtm, 2);
    matvec(ms, wm2m_w, wm2m_b, 128, v_m2m, 1);
    matvec(ms, wmaster_w, wmaster_b, 128, v_mself, 1);
    matvec(v_m2m, wzm2_w, wzm2_b, 128, v_t2, 0);
    matvec(v_mself, wzs1_w, wzs1_b, 128, v_ts1, 0);
    matvec(v_mtm, wzs2_w, wzs2_b, 128, v_ts2, 0);

    if (t < 128) {
        float z = sig1(v_ts1[t] + v_ts2[t]);
        v_hsup[t] = (1.f-z)*v_mself[t] + z*v_mtm[t];
        m2m_out[(size_t)b*128 + t] = v_m2m[t];
        t2_out[(size_t)b*128 + t]  = v_t2[t];
    }
    __syncthreads();

    for (int j = t; j < 384; j += 256) {
        float a = 0.f, h2 = 0.f;
        for (int k = 0; k < 128; ++k) {
            a  += v_hsup[k]*WTih[(size_t)k*384 + j];
            h2 += ms[k]*WThh[(size_t)k*384 + j];
        }
        gi[j] = a + bih[j];
        gh2[j] = h2 + bhh[j];
    }
    __syncthreads();
    if (t < 128) {
        float r = sig1(gi[t] + gh2[t]);
        float z = sig1(gi[128+t] + gh2[128+t]);
        float n = tanhf(gi[256+t] + r*gh2[256+t]);
        master[(size_t)b*128 + t] = (1.f-z)*n + z*ms[t];
    }
}

// ---------------------------------------------------------------------------
// u1: nl = segsum_s gelu(concat(vf[aa], e[ba]) @ u1 + b)*nbm -> bf16 planes
// ---------------------------------------------------------------------------
__global__ __launch_bounds__(256) void u1_kernel(
    const short* __restrict__ vfh, const short* __restrict__ vfl,
    const short* __restrict__ eh, const short* __restrict__ el,
    const short* __restrict__ WT, const float* __restrict__ bias,
    const int* __restrict__ aadj, const int* __restrict__ badj,
    const float* __restrict__ nbm,
    short* __restrict__ nlh, short* __restrict__ nll)
{
    __shared__ float red[4][16][132];
    const int t = threadIdx.x;
    const int lane = t & 63, wv = t >> 6;
    const int quad = lane >> 4, ml = lane & 15;
    const int m0 = blockIdx.x*128 + wv*32;
    const int r0 = m0 + ml, r1 = m0 + 16 + ml;
    const int ga0 = aadj[r0], ga1 = aadj[r1];
    const int gb0 = badj[r0], gb1 = badj[r1];

    f32x4 acc[16];
    #pragma unroll
    for (int i = 0; i < 16; ++i) acc[i] = (f32x4){0.f,0.f,0.f,0.f};
    const short* wcol = WT + (size_t)ml*160;

    #pragma unroll
    for (int kc = 0; kc < 5; ++kc) {
        const int kq = kc*32 + quad*8;
        bf16x8 a0h, a0l, a1h, a1l;
        if (kq < 128) {
            a0h = *(const bf16x8*)(vfh + (size_t)ga0*128 + kq);
            a0l = *(const bf16x8*)(vfl + (size_t)ga0*128 + kq);
            a1h = *(const bf16x8*)(vfh + (size_t)ga1*128 + kq);
            a1l = *(const bf16x8*)(vfl + (size_t)ga1*128 + kq);
        } else if (kq == 128) {
            a0h = *(const bf16x8*)(eh + (size_t)gb0*8);
            a0l = *(const bf16x8*)(el + (size_t)gb0*8);
            a1h = *(const bf16x8*)(eh + (size_t)gb1*8);
            a1l = *(const bf16x8*)(el + (size_t)gb1*8);
        } else {
            #pragma unroll
            for (int j = 0; j < 8; ++j) { a0h[j]=0; a0l[j]=0; a1h[j]=0; a1l[j]=0; }
        }
        #pragma unroll
        for (int nt = 0; nt < 8; ++nt) {
            const short* bp = wcol + (size_t)nt*16*160 + kq;
            bf16x8 bh = *(const bf16x8*)bp;
            bf16x8 bl = *(const bf16x8*)(bp + 61440);
            MFMA3(acc[nt],   a0h, a0l, bh, bl);
            MFMA3(acc[8+nt], a1h, a1l, bh, bl);
        }
    }

    #pragma unroll
    for (int mt = 0; mt < 2; ++mt) {
        __syncthreads();
        #pragma unroll
        for (int nt = 0; nt < 8; ++nt) {
            int col = nt*16 + ml;
            float bj = bias[col];
            #pragma unroll
            for (int r = 0; r < 4; ++r) {
                int gm = m0 + mt*16 + quad*4 + r;
                red[wv][quad*4+r][col] = gelu1(acc[mt*8+nt][r] + bj) * nbm[gm];
            }
        }
        __syncthreads();
        #pragma unroll
        for (int q = 0; q < 4; ++q) {
            int idx = lane*4 + q;
            int seg = idx >> 7, col = idx & 127;
            float s = 0.f;
            #pragma unroll
            for (int ss = 0; ss < 8; ++ss) s += red[wv][seg*8+ss][col];
            size_t orow = (size_t)(m0/8 + mt*2 + seg)*128 + col;
            short h_, l_; split2(s, h_, l_);
            nlh[orow] = h_; nll[orow] = l_;
        }
    }
}

// ---------------------------------------------------------------------------
// embed: vf = gelu((atomf[vertex]*vm)@emb + b); dual-store h0 + bf16 planes.
// ---------------------------------------------------------------------------
__global__ __launch_bounds__(256) void embed_kernel(
    const float* __restrict__ atomf, const int* __restrict__ vertex,
    const float* __restrict__ vmask,
    const short* __restrict__ WT, const float* __restrict__ bias,
    float* __restrict__ vf, float* __restrict__ h0,
    short* __restrict__ vfh, short* __restrict__ vfl)
{
    const int t = threadIdx.x;
    const int lane = t & 63, wv = t >> 6;
    const int quad = lane >> 4, ml = lane & 15;
    const int m0 = blockIdx.x*128 + wv*32;
    const int r0 = m0 + ml, r1 = m0 + 16 + ml;
    const int ga0 = vertex[r0], ga1 = vertex[r1];
    const float vm0 = vmask[r0], vm1 = vmask[r1];

    f32x4 acc[16];
    #pragma unroll
    for (int i = 0; i < 16; ++i) acc[i] = (f32x4){0.f,0.f,0.f,0.f};
    const short* wcol = WT + (size_t)ml*96;

    #pragma unroll
    for (int kc = 0; kc < 3; ++kc) {
        const int kq = kc*32 + quad*8;
        float av0[8], av1[8];
        const float* p0r = atomf + (size_t)ga0*AF + kq;
        const float* p1r = atomf + (size_t)ga1*AF + kq;
        #pragma unroll
        for (int j2 = 0; j2 < 4; ++j2) {
            int k = kq + 2*j2;
            if (k + 2 <= AF) {
                float2 v0 = *(const float2*)(p0r + 2*j2);
                float2 v1 = *(const float2*)(p1r + 2*j2);
                av0[2*j2]=v0.x*vm0; av0[2*j2+1]=v0.y*vm0;
                av1[2*j2]=v1.x*vm1; av1[2*j2+1]=v1.y*vm1;
            } else { av0[2*j2]=0.f; av0[2*j2+1]=0.f; av1[2*j2]=0.f; av1[2*j2+1]=0.f; }
        }
        bf16x8 a0h, a0l, a1h, a1l;
        #pragma unroll
        for (int j = 0; j < 8; ++j) {
            short h, l;
            split2(av0[j], h, l); a0h[j]=h; a0l[j]=l;
            split2(av1[j], h, l); a1h[j]=h; a1l[j]=l;
        }
        #pragma unroll
        for (int nt = 0; nt < 8; ++nt) {
            const short* bp = wcol + (size_t)nt*16*96 + kq;
            bf16x8 bh = *(const bf16x8*)bp;
            bf16x8 bl = *(const bf16x8*)(bp + 12288);
            MFMA3(acc[nt],   a0h, a0l, bh, bl);
            MFMA3(acc[8+nt], a1h, a1l, bh, bl);
        }
    }

    #pragma unroll
    for (int mt = 0; mt < 2; ++mt) {
        #pragma unroll
        for (int nt = 0; nt < 8; ++nt) {
            int col = nt*16 + ml;
            float bj = bias[col];
            #pragma unroll
            for (int r = 0; r < 4; ++r) {
                int gm = m0 + mt*16 + quad*4 + r;
                float v = gelu1(acc[mt*8+nt][r] + bj);
                size_t off = (size_t)gm*128 + col;
                vf[off] = v; h0[off] = v;
                short h_, l_; split2(v, h_, l_);
                vfh[off] = h_; vfl[off] = l_;
            }
        }
    }
}

// ---------------------------------------------------------------------------
// merged weight-prep kernel (all converts + transposes)
// ---------------------------------------------------------------------------
__device__ __forceinline__ void cvt_t(const float* __restrict__ src, short* __restrict__ dst,
                                      int i, int K, int Kpad, int total)
{
    int z = i / (128*Kpad); int rem = i - z*128*Kpad;
    int col = rem / Kpad; int k = rem - col*Kpad;
    float v = (k < K) ? src[(size_t)z*K*128 + (size_t)k*128 + col] : 0.f;
    short h, l; split2(v, h, l);
    dst[i] = h; dst[total + i] = l;
}

__global__ void wprep_kernel(
    const float* __restrict__ emb_w, const float* __restrict__ wvm_w,
    const float* __restrict__ u1_w, const float* __restrict__ u2_w,
    const float* __restrict__ fu_w, const float* __restrict__ wzm1_w,
    const float* __restrict__ g_wih, const float* __restrict__ g_whh,
    const float* __restrict__ gm_wih, const float* __restrict__ gm_whh,
    short* __restrict__ wt_emb, short* __restrict__ wt_wvm,
    short* __restrict__ wt_u1, short* __restrict__ wt_u2,
    short* __restrict__ wt_fu, short* __restrict__ wt_wzm1,
    short* __restrict__ wt_gih, short* __restrict__ wt_ghh,
    float* __restrict__ WTih_s, float* __restrict__ WThh_s)
{
    int i = blockIdx.x*256 + threadIdx.x;
    if (i < 12288) cvt_t(emb_w, wt_emb, i, 82, 96, 12288);
    else if (i < 208896) cvt_t(wvm_w, wt_wvm, i-12288, 128, 128, 196608);
    else if (i < 270336) cvt_t(u1_w, wt_u1, i-208896, 134, 160, 61440);
    else if (i < 368640) cvt_t(u2_w, wt_u2, i-270336, 256, 256, 98304);
    else if (i < 417792) cvt_t(fu_w, wt_fu, i-368640, 128, 128, 49152);
    else if (i < 466944) cvt_t(wzm1_w, wt_wzm1, i-417792, 128, 128, 49152);
    else if (i < 516096) { int j = i-466944; short h,l; split2(g_wih[j],h,l); wt_gih[j]=h; wt_gih[49152+j]=l; }
    else if (i < 565248) { int j = i-516096; short h,l; split2(g_whh[j],h,l); wt_ghh[j]=h; wt_ghh[49152+j]=l; }
    else if (i < 614400) { int o = i-565248; int k = o/384, j = o-k*384; WTih_s[o] = gm_wih[j*128 + k]; }
    else if (i < 663552) { int o = i-614400; int k = o/384, j = o-k*384; WThh_s[o] = gm_whh[j*128 + k]; }
}

__global__ void e_gather_kernel(const float* __restrict__ bondf, const int* __restrict__ edge,
                                short* __restrict__ eh, short* __restrict__ el)
{
    int idx = blockIdx.x*256 + threadIdx.x;
    if (idx >= BB*EE*8) return;
    int m = idx >> 3, j = idx & 7;
    float v = (j < BF) ? bondf[edge[m]*BF + j] : 0.f;
    short h, l; split2(v, h, l);
    eh[idx] = h; el[idx] = l;
}

__global__ __launch_bounds__(256) void master_init_kernel(const float* __restrict__ vf,
                                                          const float* __restrict__ vm,
                                                          float* __restrict__ master)
{
    __shared__ float red[256];
    int b = blockIdx.x; int t = threadIdx.x; int hcol = t & 127; int half = t >> 7;
    float s = 0.f;
    for (int n = half; n < NN; n += 2)
        s += vf[((size_t)b*NN + n)*HH + hcol] * vm[b*NN + n];
    red[t] = s; __syncthreads();
    if (half == 0) master[b*HH + hcol] = red[hcol] + red[hcol + 128];
}

__global__ void copy_out_kernel(const float* __restrict__ vf, const float* __restrict__ master,
                                float* __restrict__ out)
{
    int i = blockIdx.x*256 + threadIdx.x;
    const int nvf4 = SLAB/4;
    if (i < nvf4) ((float4*)out)[i] = ((const float4*)vf)[i];
    else ((float4*)out)[i] = ((const float4*)master)[i - nvf4];
}

// ---------------------------------------------------------------------------
extern "C" void kernel_launch(void* const* d_in, const int* in_sizes, int n_in,
                              void* d_out, int out_size, void* d_ws, size_t ws_size,
                              hipStream_t stream)
{
    (void)in_sizes; (void)n_in; (void)out_size; (void)ws_size;
    const float* vmask = (const float*)d_in[1];
    const int*   vertex= (const int*)d_in[2];
    const int*   edge  = (const int*)d_in[3];
    const int*   aadj  = (const int*)d_in[4];
    const int*   badj  = (const int*)d_in[5];
    const float* nbm   = (const float*)d_in[6];
    const float* atomf = (const float*)d_in[7];
    const float* bondf = (const float*)d_in[8];
    const float* emb_w = (const float*)d_in[9];
    const float* emb_b = (const float*)d_in[10];
    const float* u1_w  = (const float*)d_in[11];
    const float* u1_b  = (const float*)d_in[12];
    const float* u2_w  = (const float*)d_in[13];
    const float* u2_b  = (const float*)d_in[14];
    const float* fu_w  = (const float*)d_in[15];
    const float* fu_b  = (const float*)d_in[16];
    const float* wvm_w = (const float*)d_in[17];
    const float* wvm_b = (const float*)d_in[18];
    const float* wmain_w=(const float*)d_in[19];
    const float* wmain_b=(const float*)d_in[20];
    const float* wbmm_w= (const float*)d_in[21];
    const float* wbmm_b= (const float*)d_in[22];
    const float* khead_w=(const float*)d_in[23];
    const float* khead_b=(const float*)d_in[24];
    const float* wmaster_w=(const float*)d_in[25];
    const float* wmaster_b=(const float*)d_in[26];
    const float* wm2m_w= (const float*)d_in[27];
    const float* wm2m_b= (const float*)d_in[28];
    const float* wzm1_w= (const float*)d_in[29];
    const float* wzm1_b= (const float*)d_in[30];
    const float* wzm2_w= (const float*)d_in[31];
    const float* wzm2_b= (const float*)d_in[32];
    const float* wzs1_w= (const float*)d_in[33];
    const float* wzs1_b= (const float*)d_in[34];
    const float* wzs2_w= (const float*)d_in[35];
    const float* wzs2_b= (const float*)d_in[36];
    const float* g_wih = (const float*)d_in[37];
    const float* g_whh = (const float*)d_in[38];
    const float* g_bih = (const float*)d_in[39];
    const float* g_bhh = (const float*)d_in[40];
    const float* gm_wih= (const float*)d_in[41];
    const float* gm_whh= (const float*)d_in[42];
    const float* gm_bih= (const float*)d_in[43];
    const float* gm_bhh= (const float*)d_in[44];

    float* ws     = (float*)d_ws;
    float* vf     = ws;
    float* h0     = vf + SLAB;
    float* score  = h0 + SLAB;
    float* master = score + BB*KK*NN;
    float* m2m    = master + BB*HH;
    float* t2     = m2m + BB*HH;
    float* WTih_s = t2 + BB*HH;
    float* WThh_s = WTih_s + 128*384;
    short* vfh    = (short*)(WThh_s + 128*384);
    short* vfl    = vfh + SLAB;
    short* nlh    = vfl + SLAB;
    short* nll    = nlh + SLAB;
    short* eh     = nll + SLAB;
    short* el     = eh + BB*EE*8;
    short* wt_emb   = el + BB*EE*8;
    short* wt_wvm   = wt_emb   + 2*12288;
    short* wt_u1    = wt_wvm   + 2*196608;
    short* wt_u2    = wt_u1    + 2*61440;
    short* wt_fu    = wt_u2    + 2*98304;
    short* wt_wzm1  = wt_fu    + 2*49152;
    short* wt_gih   = wt_wzm1  + 2*49152;
    short* wt_ghh   = wt_gih   + 2*49152;

    wprep_kernel<<<2592, 256, 0, stream>>>(
        emb_w, wvm_w, u1_w, u2_w, fu_w, wzm1_w, g_wih, g_whh, gm_wih, gm_whh,
        wt_emb, wt_wvm, wt_u1, wt_u2, wt_fu, wt_wzm1, wt_gih, wt_ghh,
        WTih_s, WThh_s);

    e_gather_kernel<<<(BB*EE*8 + 255)/256, 256, 0, stream>>>(bondf, edge, eh, el);

    embed_kernel<<<256, 256, 0, stream>>>(atomf, vertex, vmask, wt_emb, emb_b,
                                          vf, h0, vfh, vfl);
    master_init_kernel<<<BB, 256, 0, stream>>>(vf, vmask, master);

    for (int i = 0; i < LL; ++i) {
        float theta = logf(0.5f/(float)(i+1) + 1.f);

        mvscore_kernel<<<dim3(256,1,4), 256, 0, stream>>>(
            vfh, vfl, wt_wvm + (size_t)i*4*16384, wvm_b + (size_t)i*4*128,
            master, wbmm_w + (size_t)i*KK*HH, wbmm_b + (size_t)i*KK, score);

        postatt<<<BB, 256, 0, stream>>>(
            score, vmask, vf, master,
            wmain_w + (size_t)i*KK*HH*HH, wmain_b + (size_t)i*KK*HH,
            khead_w + (size_t)i*KK*HH*HH, khead_b + i*HH,
            wm2m_w + (size_t)i*HH*HH, wm2m_b + i*HH,
            wmaster_w + (size_t)i*HH*HH, wmaster_b + i*HH,
            wzm2_w + (size_t)i*HH*HH, wzm2_b + i*HH,
            wzs1_w + (size_t)i*HH*HH, wzs1_b + i*HH,
            wzs2_w + (size_t)i*HH*HH, wzs2_b + i*HH,
            WTih_s, WThh_s, gm_bih, gm_bhh,
            m2m, t2);

        u1_kernel<<<2048, 256, 0, stream>>>(
            vfh, vfl, eh, el, wt_u1 + (size_t)i*128*160, u1_b + i*HH,
            aadj, badj, nbm, nlh, nll);

        vchain<<<2048, 256, 0, stream>>>(
            nlh, nll, vf, vfh, vfl, h0,
            wt_u2 + (size_t)i*128*256, u2_b + i*HH,
            wt_fu + (size_t)i*16384, fu_b + i*HH,
            wt_wzm1 + (size_t)i*16384, wzm1_b + i*HH,
            wt_gih, wt_ghh, g_bih, g_bhh,
            t2, m2m, theta);
    }

    copy_out_kernel<<<(SLAB + BB*HH)/4/256, 256, 0, stream>>>(vf, master, (float*)d_out);
}

// Round 8
// 1459.444 us; speedup vs baseline: 1.2187x; 1.2187x over previous
//
#include <hip/hip_runtime.h>
#include <hip/hip_bf16.h>
#include <cmath>

// Problem constants
#define BB 64
#define NN 512
#define NBS 8
#define EE 2048
#define HH 128
#define LL 3
#define KK 4
#define AF 82
#define BF 6
#define SLAB 4194304   // B*N*H floats

typedef __attribute__((ext_vector_type(8))) short bf16x8;
typedef __attribute__((ext_vector_type(4))) float f32x4;

__device__ __forceinline__ float gelu1(float x){ return 0.5f*x*(1.f+erff(x*0.7071067811865475f)); }
__device__ __forceinline__ float sig1(float x){ return 1.f/(1.f+expf(-x)); }
__device__ __forceinline__ short f2bs(float x){ __hip_bfloat16 b=__float2bfloat16(x); return *reinterpret_cast<short*>(&b); }
__device__ __forceinline__ float bs2f(short s){ unsigned u = ((unsigned)(unsigned short)s) << 16; union{unsigned u; float f;} c; c.u=u; return c.f; }
__device__ __forceinline__ void split2(float v, short& hi, short& lo){ hi = f2bs(v); lo = f2bs(v - bs2f(hi)); }

#define MFMA3(ACC, AH, AL, BH, BL) \
    ACC = __builtin_amdgcn_mfma_f32_16x16x32_bf16(AH, BH, ACC, 0,0,0); \
    ACC = __builtin_amdgcn_mfma_f32_16x16x32_bf16(AL, BH, ACC, 0,0,0); \
    ACC = __builtin_amdgcn_mfma_f32_16x16x32_bf16(AH, BL, ACC, 0,0,0);

// ---------------------------------------------------------------------------
// vchain (col-split): u2 -> support -> fu -> sv -> wzm1 z-gate -> GRU.
// Block = 256 thr = 4 waves, 16 rows; wave owns 32 cols. Grid = B*N/16 = 2048.
// Intermediates in LDS as hi/lo bf16 planes (split once at producer).
// ---------------------------------------------------------------------------
__global__ __launch_bounds__(256) void vchain(
    const short* __restrict__ nlh, const short* __restrict__ nll,
    float* __restrict__ vf, short* __restrict__ vfh, short* __restrict__ vfl,
    const float* __restrict__ h0,
    const short* __restrict__ wu2, const float* __restrict__ u2b,
    const short* __restrict__ wfu, const float* __restrict__ fub,
    const short* __restrict__ wzm, const float* __restrict__ zmb,
    const short* __restrict__ wih, const short* __restrict__ whh,
    const float* __restrict__ bih, const float* __restrict__ bhh,
    const float* __restrict__ t2, const float* __restrict__ m2m,
    float theta)
{
    __shared__ __align__(16) short sh[16*136];
    __shared__ __align__(16) short sl[16*136];
    const int t = threadIdx.x;
    const int lane = t & 63, wv = t >> 6;
    const int quad = lane >> 4, ml = lane & 15;
    const int base = blockIdx.x * 16;
    const int arow = base + ml;
    const int bb = base >> 9;
    const int c0 = wv*32 + ml;          // wave owns cols c0 and c0+16
    const int kq0 = quad*8;

    f32x4 acc0 = (f32x4){0.f,0.f,0.f,0.f}, acc1 = (f32x4){0.f,0.f,0.f,0.f};

    // ---- stage A: hi = concat(nl, vf) @ u2, K=256
    #pragma unroll
    for (int kc = 0; kc < 8; ++kc) {
        const int kq = kc*32 + kq0;
        bf16x8 ah, al;
        if (kc < 4) {
            ah = *(const bf16x8*)(nlh + (size_t)arow*128 + kq);
            al = *(const bf16x8*)(nll + (size_t)arow*128 + kq);
        } else {
            ah = *(const bf16x8*)(vfh + (size_t)arow*128 + kq - 128);
            al = *(const bf16x8*)(vfl + (size_t)arow*128 + kq - 128);
        }
        const short* bp0 = wu2 + (size_t)c0*256 + kq;
        const short* bp1 = wu2 + (size_t)(c0+16)*256 + kq;
        MFMA3(acc0, ah, al, *(const bf16x8*)bp0, *(const bf16x8*)(bp0+98304));
        MFMA3(acc1, ah, al, *(const bf16x8*)bp1, *(const bf16x8*)(bp1+98304));
    }
    f32x4 sup0, sup1;
    {
        float bj0 = u2b[c0], bj1 = u2b[c0+16];
        #pragma unroll
        for (int r = 0; r < 4; ++r) {
            int row = base + quad*4 + r;
            sup0[r] = 0.9f*(acc0[r] + bj0) + 0.1f*h0[(size_t)row*128 + c0];
            sup1[r] = 0.9f*(acc1[r] + bj1) + 0.1f*h0[(size_t)row*128 + c0+16];
        }
    }
    #pragma unroll
    for (int r = 0; r < 4; ++r) {
        int lrow = quad*4 + r;
        short h_, l_;
        split2(sup0[r], h_, l_); sh[lrow*136 + c0] = h_; sl[lrow*136 + c0] = l_;
        split2(sup1[r], h_, l_); sh[lrow*136 + c0+16] = h_; sl[lrow*136 + c0+16] = l_;
    }
    __syncthreads();

    // ---- stage B: sv = theta*(sup@fu + b) + (1-theta)*sup
    acc0 = (f32x4){0.f,0.f,0.f,0.f}; acc1 = (f32x4){0.f,0.f,0.f,0.f};
    #pragma unroll
    for (int kc = 0; kc < 4; ++kc) {
        const int kq = kc*32 + kq0;
        bf16x8 xh = *(const bf16x8*)&sh[ml*136 + kq];
        bf16x8 xl = *(const bf16x8*)&sl[ml*136 + kq];
        const short* bp0 = wfu + (size_t)c0*128 + kq;
        const short* bp1 = wfu + (size_t)(c0+16)*128 + kq;
        MFMA3(acc0, xh, xl, *(const bf16x8*)bp0, *(const bf16x8*)(bp0+49152));
        MFMA3(acc1, xh, xl, *(const bf16x8*)bp1, *(const bf16x8*)(bp1+49152));
    }
    f32x4 sv0, sv1;
    {
        float bj0 = fub[c0], bj1 = fub[c0+16];
        #pragma unroll
        for (int r = 0; r < 4; ++r) {
            sv0[r] = theta*(acc0[r] + bj0) + (1.f-theta)*sup0[r];
            sv1[r] = theta*(acc1[r] + bj1) + (1.f-theta)*sup1[r];
        }
    }
    __syncthreads();
    #pragma unroll
    for (int r = 0; r < 4; ++r) {
        int lrow = quad*4 + r;
        short h_, l_;
        split2(sv0[r], h_, l_); sh[lrow*136 + c0] = h_; sl[lrow*136 + c0] = l_;
        split2(sv1[r], h_, l_); sh[lrow*136 + c0+16] = h_; sl[lrow*136 + c0+16] = l_;
    }
    __syncthreads();

    // ---- stage C: z = sig(sv@wzm1 + b + t2[b]); hid = (1-z)*sv + z*m2m[b]
    acc0 = (f32x4){0.f,0.f,0.f,0.f}; acc1 = (f32x4){0.f,0.f,0.f,0.f};
    #pragma unroll
    for (int kc = 0; kc < 4; ++kc) {
        const int kq = kc*32 + kq0;
        bf16x8 xh = *(const bf16x8*)&sh[ml*136 + kq];
        bf16x8 xl = *(const bf16x8*)&sl[ml*136 + kq];
        const short* bp0 = wzm + (size_t)c0*128 + kq;
        const short* bp1 = wzm + (size_t)(c0+16)*128 + kq;
        MFMA3(acc0, xh, xl, *(const bf16x8*)bp0, *(const bf16x8*)(bp0+49152));
        MFMA3(acc1, xh, xl, *(const bf16x8*)bp1, *(const bf16x8*)(bp1+49152));
    }
    f32x4 hid0, hid1;
    {
        float bj0 = zmb[c0], bj1 = zmb[c0+16];
        float t20 = t2[(size_t)bb*128 + c0], t21 = t2[(size_t)bb*128 + c0+16];
        float m20 = m2m[(size_t)bb*128 + c0], m21 = m2m[(size_t)bb*128 + c0+16];
        #pragma unroll
        for (int r = 0; r < 4; ++r) {
            float z0 = sig1(acc0[r] + bj0 + t20);
            float z1 = sig1(acc1[r] + bj1 + t21);
            hid0[r] = (1.f-z0)*sv0[r] + z0*m20;
            hid1[r] = (1.f-z1)*sv1[r] + z1*m21;
        }
    }
    __syncthreads();
    #pragma unroll
    for (int r = 0; r < 4; ++r) {
        int lrow = quad*4 + r;
        short h_, l_;
        split2(hid0[r], h_, l_); sh[lrow*136 + c0] = h_; sl[lrow*136 + c0] = l_;
        split2(hid1[r], h_, l_); sh[lrow*136 + c0+16] = h_; sl[lrow*136 + c0+16] = l_;
    }
    __syncthreads();

    // ---- stage D: GRU (vf frags cached in regs across gates)
    bf16x8 xfh[4], xfl[4], vh_[4], vl_[4];
    #pragma unroll
    for (int kc = 0; kc < 4; ++kc) {
        const int kq = kc*32 + kq0;
        xfh[kc] = *(const bf16x8*)&sh[ml*136 + kq];
        xfl[kc] = *(const bf16x8*)&sl[ml*136 + kq];
        vh_[kc] = *(const bf16x8*)(vfh + (size_t)arow*128 + kq);
        vl_[kc] = *(const bf16x8*)(vfl + (size_t)arow*128 + kq);
    }
    f32x4 rg0, rg1, zg0, zg1;
    #pragma unroll
    for (int g = 0; g < 3; ++g) {
        f32x4 gi0 = (f32x4){0.f,0.f,0.f,0.f}, gi1 = (f32x4){0.f,0.f,0.f,0.f};
        f32x4 gh0 = (f32x4){0.f,0.f,0.f,0.f}, gh1 = (f32x4){0.f,0.f,0.f,0.f};
        #pragma unroll
        for (int kc = 0; kc < 4; ++kc) {
            const int kq = kc*32 + kq0;
            const size_t w0 = (size_t)(g*128 + c0)*128 + kq;
            const size_t w1 = (size_t)(g*128 + c0+16)*128 + kq;
            MFMA3(gi0, xfh[kc], xfl[kc], *(const bf16x8*)(wih+w0), *(const bf16x8*)(wih+w0+49152));
            MFMA3(gi1, xfh[kc], xfl[kc], *(const bf16x8*)(wih+w1), *(const bf16x8*)(wih+w1+49152));
            MFMA3(gh0, vh_[kc], vl_[kc], *(const bf16x8*)(whh+w0), *(const bf16x8*)(whh+w0+49152));
            MFMA3(gh1, vh_[kc], vl_[kc], *(const bf16x8*)(whh+w1), *(const bf16x8*)(whh+w1+49152));
        }
        if (g == 0) {
            float b10 = bih[c0], b20 = bhh[c0], b11 = bih[c0+16], b21 = bhh[c0+16];
            #pragma unroll
            for (int r = 0; r < 4; ++r) {
                rg0[r] = sig1(gi0[r] + b10 + gh0[r] + b20);
                rg1[r] = sig1(gi1[r] + b11 + gh1[r] + b21);
            }
        } else if (g == 1) {
            float b10 = bih[128+c0], b20 = bhh[128+c0], b11 = bih[128+c0+16], b21 = bhh[128+c0+16];
            #pragma unroll
            for (int r = 0; r < 4; ++r) {
                zg0[r] = sig1(gi0[r] + b10 + gh0[r] + b20);
                zg1[r] = sig1(gi1[r] + b11 + gh1[r] + b21);
            }
        } else {
            float b10 = bih[256+c0], b20 = bhh[256+c0], b11 = bih[256+c0+16], b21 = bhh[256+c0+16];
            #pragma unroll
            for (int r = 0; r < 4; ++r) {
                int row = base + quad*4 + r;
                size_t off0 = (size_t)row*128 + c0;
                size_t off1 = off0 + 16;
                float n0 = tanhf(gi0[r] + b10 + rg0[r]*(gh0[r] + b20));
                float n1 = tanhf(gi1[r] + b11 + rg1[r]*(gh1[r] + b21));
                float o0 = (1.f-zg0[r])*n0 + zg0[r]*vf[off0];
                float o1 = (1.f-zg1[r])*n1 + zg1[r]*vf[off1];
                vf[off0] = o0; vf[off1] = o1;
                short h_, l_;
                split2(o0, h_, l_); vfh[off0] = h_; vfl[off0] = l_;
                split2(o1, h_, l_); vfh[off1] = h_; vfl[off1] = l_;
            }
        }
    }
}

// ---------------------------------------------------------------------------
// mvscore: one head per blockIdx.z; block = 128 rows. Grid (256,1,4).
// ---------------------------------------------------------------------------
__global__ __launch_bounds__(256) void mvscore_kernel(
    const short* __restrict__ vfh, const short* __restrict__ vfl,
    const short* __restrict__ WT, const float* __restrict__ bias,
    const float* __restrict__ master,
    const float* __restrict__ wbw, const float* __restrict__ wbb,
    float* __restrict__ score)
{
    const int t = threadIdx.x;
    const int lane = t & 63, wv = t >> 6;
    const int quad = lane >> 4, ml = lane & 15;
    const int k = blockIdx.z;
    const int tile = blockIdx.x;
    const int b = tile >> 2;
    const int r0 = tile*128 + wv*32 + ml;
    const int r1 = r0 + 16;

    bf16x8 a0h[4], a0l[4], a1h[4], a1l[4];
    #pragma unroll
    for (int kc = 0; kc < 4; ++kc) {
        const int kq = kc*32 + quad*8;
        a0h[kc] = *(const bf16x8*)(vfh + (size_t)r0*128 + kq);
        a0l[kc] = *(const bf16x8*)(vfl + (size_t)r0*128 + kq);
        a1h[kc] = *(const bf16x8*)(vfh + (size_t)r1*128 + kq);
        a1l[kc] = *(const bf16x8*)(vfl + (size_t)r1*128 + kq);
    }

    f32x4 acc[16];
    #pragma unroll
    for (int i = 0; i < 16; ++i) acc[i] = (f32x4){0.f,0.f,0.f,0.f};
    const short* wcol = WT + (size_t)k*16384 + (size_t)ml*128;
    #pragma unroll
    for (int kc = 0; kc < 4; ++kc) {
        const int kq = kc*32 + quad*8;
        #pragma unroll
        for (int nt = 0; nt < 8; ++nt) {
            const short* bp = wcol + (size_t)nt*16*128 + kq;
            bf16x8 bh = *(const bf16x8*)bp;
            bf16x8 bl = *(const bf16x8*)(bp + 196608);
            MFMA3(acc[nt],   a0h[kc], a0l[kc], bh, bl);
            MFMA3(acc[8+nt], a1h[kc], a1l[kc], bh, bl);
        }
    }
    float wv8[8], bj8[8];
    #pragma unroll
    for (int nt = 0; nt < 8; ++nt) {
        int col = nt*16 + ml;
        wv8[nt] = master[(size_t)b*128 + col] * wbw[(size_t)k*128 + col];
        bj8[nt] = bias[(size_t)k*128 + col];
    }
    float kb = wbb[k];
    #pragma unroll
    for (int mt = 0; mt < 2; ++mt) {
        #pragma unroll
        for (int r = 0; r < 4; ++r) {
            float s = 0.f;
            #pragma unroll
            for (int nt = 0; nt < 8; ++nt)
                s += tanhf(acc[mt*8+nt][r] + bj8[nt]) * wv8[nt];
            s += __shfl_xor(s, 1); s += __shfl_xor(s, 2);
            s += __shfl_xor(s, 4); s += __shfl_xor(s, 8);
            if (ml == 0) {
                int nloc = (tile & 3)*128 + wv*32 + mt*16 + quad*4 + r;
                score[((size_t)(b*KK + k))*NN + nloc] = s + kb;
            }
        }
    }
}

// ---------------------------------------------------------------------------
// attctx: softmax(score row) -> satt + ctx = att @ vf. One block per (b,k).
// ---------------------------------------------------------------------------
__global__ __launch_bounds__(256) void attctx_kernel(
    const float* __restrict__ score, const float* __restrict__ vm,
    const float* __restrict__ vf,
    float* __restrict__ satt, float* __restrict__ ctx)
{
    __shared__ float red[256];
    __shared__ float att[512];
    const int t = threadIdx.x;
    const int bk = blockIdx.x, b = bk >> 2;
    float v0 = score[(size_t)bk*NN + t], v1 = score[(size_t)bk*NN + 256 + t];
    red[t] = fmaxf(v0, v1); __syncthreads();
    for (int s = 128; s; s >>= 1) { if (t < s) red[t] = fmaxf(red[t], red[t+s]); __syncthreads(); }
    float mx = red[0]; __syncthreads();
    float e0 = expf(v0 - mx) * vm[b*NN + t];
    float e1 = expf(v1 - mx) * vm[b*NN + t + 256];
    red[t] = e0 + e1; __syncthreads();
    for (int s = 128; s; s >>= 1) { if (t < s) red[t] += red[t+s]; __syncthreads(); }
    float sum = red[0];
    float inv = 1.f / (sum + 1e-6f);
    att[t] = e0*inv; att[t+256] = e1*inv;
    if (t == 0) satt[bk] = sum*inv;
    __syncthreads();
    const int d = t & 127, h = t >> 7;
    float acc = 0.f;
    const float* V = vf + (size_t)b*NN*HH;
    #pragma unroll 8
    for (int n = h*256; n < h*256 + 256; ++n) acc += att[n]*V[(size_t)n*HH + d];
    red[t] = acc; __syncthreads();
    if (t < 128) ctx[(size_t)bk*HH + t] = red[t] + red[t+128];
}

// ---------------------------------------------------------------------------
// master_fused: kmm from ctx, mtm, m2m, mself, t2, hidden_super, master GRU.
// grid = 64 blocks.
// ---------------------------------------------------------------------------
__global__ __launch_bounds__(256) void master_fused(
    const float* __restrict__ ctx, const float* __restrict__ satt,
    float* __restrict__ master,
    const float* __restrict__ wmain_w, const float* __restrict__ wmain_b,
    const float* __restrict__ khead_w, const float* __restrict__ khead_b,
    const float* __restrict__ wm2m_w,  const float* __restrict__ wm2m_b,
    const float* __restrict__ wmaster_w, const float* __restrict__ wmaster_b,
    const float* __restrict__ wzm2_w,  const float* __restrict__ wzm2_b,
    const float* __restrict__ wzs1_w,  const float* __restrict__ wzs1_b,
    const float* __restrict__ wzs2_w,  const float* __restrict__ wzs2_b,
    const float* __restrict__ WTih, const float* __restrict__ WThh,
    const float* __restrict__ bih, const float* __restrict__ bhh,
    float* __restrict__ m2m_out, float* __restrict__ t2_out)
{
    __shared__ float xs[512], ms[128];
    __shared__ float v_mtm[128], v_m2m[128], v_mself[128], v_t2[128];
    __shared__ float v_ts1[128], v_ts2[128], v_hsup[128];
    __shared__ float gi[384], gh2[384];
    __shared__ float red[256];
    const int t = threadIdx.x;
    const int b = blockIdx.x;

    if (t < 128) ms[t] = master[(size_t)b*128 + t];
    __syncthreads();

    const int c = t & 127, p = t >> 7;

    #pragma unroll
    for (int k = 0; k < 4; ++k) {
        const float* cx = ctx + ((size_t)b*KK + k)*128;
        const float* Wk = wmain_w + (size_t)k*16384;
        float s = 0.f;
        for (int d = p*64; d < p*64+64; ++d) s += cx[d]*Wk[(size_t)d*128 + c];
        red[t] = s; __syncthreads();
        if (t < 128) xs[k*128 + c] = red[c] + red[c+128] + satt[(size_t)b*KK + k]*wmain_b[k*128 + c];
        __syncthreads();
    }

    auto matvec = [&](const float* src, const float* __restrict__ W,
                      const float* __restrict__ bias, int K, float* out, int act) {
        int half = K >> 1;
        int k0 = p*half, k1 = k0 + half;
        float s = 0.f;
        for (int k = k0; k < k1; ++k) s += src[k]*W[(size_t)k*128 + c];
        red[t] = s; __syncthreads();
        if (t < 128) {
            float v = red[c] + red[c+128] + bias[c];
            if (act == 1) v = gelu1(v); else if (act == 2) v = tanhf(v);
            out[c] = v;
        }
        __syncthreads();
    };

    matvec(xs, khead_w, khead_b, 512, v_mtm, 2);
    matvec(ms, wm2m_w, wm2m_b, 128, v_m2m, 1);
    matvec(ms, wmaster_w, wmaster_b, 128, v_mself, 1);
    matvec(v_m2m, wzm2_w, wzm2_b, 128, v_t2, 0);
    matvec(v_mself, wzs1_w, wzs1_b, 128, v_ts1, 0);
    matvec(v_mtm, wzs2_w, wzs2_b, 128, v_ts2, 0);

    if (t < 128) {
        float z = sig1(v_ts1[t] + v_ts2[t]);
        v_hsup[t] = (1.f-z)*v_mself[t] + z*v_mtm[t];
        m2m_out[(size_t)b*128 + t] = v_m2m[t];
        t2_out[(size_t)b*128 + t]  = v_t2[t];
    }
    __syncthreads();

    for (int j = t; j < 384; j += 256) {
        float a = 0.f, h2 = 0.f;
        for (int k = 0; k < 128; ++k) {
            a  += v_hsup[k]*WTih[(size_t)k*384 + j];
            h2 += ms[k]*WThh[(size_t)k*384 + j];
        }
        gi[j] = a + bih[j];
        gh2[j] = h2 + bhh[j];
    }
    __syncthreads();
    if (t < 128) {
        float r = sig1(gi[t] + gh2[t]);
        float z = sig1(gi[128+t] + gh2[128+t]);
        float n = tanhf(gi[256+t] + r*gh2[256+t]);
        master[(size_t)b*128 + t] = (1.f-z)*n + z*ms[t];
    }
}

// ---------------------------------------------------------------------------
// u1: nl = segsum_s gelu(concat(vf[aa], e[ba]) @ u1 + b)*nbm -> bf16 planes
// ---------------------------------------------------------------------------
__global__ __launch_bounds__(256) void u1_kernel(
    const short* __restrict__ vfh, const short* __restrict__ vfl,
    const short* __restrict__ eh, const short* __restrict__ el,
    const short* __restrict__ WT, const float* __restrict__ bias,
    const int* __restrict__ aadj, const int* __restrict__ badj,
    const float* __restrict__ nbm,
    short* __restrict__ nlh, short* __restrict__ nll)
{
    __shared__ float red[4][16][132];
    const int t = threadIdx.x;
    const int lane = t & 63, wv = t >> 6;
    const int quad = lane >> 4, ml = lane & 15;
    const int m0 = blockIdx.x*128 + wv*32;
    const int r0 = m0 + ml, r1 = m0 + 16 + ml;
    const int ga0 = aadj[r0], ga1 = aadj[r1];
    const int gb0 = badj[r0], gb1 = badj[r1];

    f32x4 acc[16];
    #pragma unroll
    for (int i = 0; i < 16; ++i) acc[i] = (f32x4){0.f,0.f,0.f,0.f};
    const short* wcol = WT + (size_t)ml*160;

    #pragma unroll
    for (int kc = 0; kc < 5; ++kc) {
        const int kq = kc*32 + quad*8;
        bf16x8 a0h, a0l, a1h, a1l;
        if (kq < 128) {
            a0h = *(const bf16x8*)(vfh + (size_t)ga0*128 + kq);
            a0l = *(const bf16x8*)(vfl + (size_t)ga0*128 + kq);
            a1h = *(const bf16x8*)(vfh + (size_t)ga1*128 + kq);
            a1l = *(const bf16x8*)(vfl + (size_t)ga1*128 + kq);
        } else if (kq == 128) {
            a0h = *(const bf16x8*)(eh + (size_t)gb0*8);
            a0l = *(const bf16x8*)(el + (size_t)gb0*8);
            a1h = *(const bf16x8*)(eh + (size_t)gb1*8);
            a1l = *(const bf16x8*)(el + (size_t)gb1*8);
        } else {
            #pragma unroll
            for (int j = 0; j < 8; ++j) { a0h[j]=0; a0l[j]=0; a1h[j]=0; a1l[j]=0; }
        }
        #pragma unroll
        for (int nt = 0; nt < 8; ++nt) {
            const short* bp = wcol + (size_t)nt*16*160 + kq;
            bf16x8 bh = *(const bf16x8*)bp;
            bf16x8 bl = *(const bf16x8*)(bp + 61440);
            MFMA3(acc[nt],   a0h, a0l, bh, bl);
            MFMA3(acc[8+nt], a1h, a1l, bh, bl);
        }
    }

    #pragma unroll
    for (int mt = 0; mt < 2; ++mt) {
        __syncthreads();
        #pragma unroll
        for (int nt = 0; nt < 8; ++nt) {
            int col = nt*16 + ml;
            float bj = bias[col];
            #pragma unroll
            for (int r = 0; r < 4; ++r) {
                int gm = m0 + mt*16 + quad*4 + r;
                red[wv][quad*4+r][col] = gelu1(acc[mt*8+nt][r] + bj) * nbm[gm];
            }
        }
        __syncthreads();
        #pragma unroll
        for (int q = 0; q < 4; ++q) {
            int idx = lane*4 + q;
            int seg = idx >> 7, col = idx & 127;
            float s = 0.f;
            #pragma unroll
            for (int ss = 0; ss < 8; ++ss) s += red[wv][seg*8+ss][col];
            size_t orow = (size_t)(m0/8 + mt*2 + seg)*128 + col;
            short h_, l_; split2(s, h_, l_);
            nlh[orow] = h_; nll[orow] = l_;
        }
    }
}

// ---------------------------------------------------------------------------
// embed: vf = gelu((atomf[vertex]*vm)@emb + b); dual-store h0 + bf16 planes.
// ---------------------------------------------------------------------------
__global__ __launch_bounds__(256) void embed_kernel(
    const float* __restrict__ atomf, const int* __restrict__ vertex,
    const float* __restrict__ vmask,
    const short* __restrict__ WT, const float* __restrict__ bias,
    float* __restrict__ vf, float* __restrict__ h0,
    short* __restrict__ vfh, short* __restrict__ vfl)
{
    const int t = threadIdx.x;
    const int lane = t & 63, wv = t >> 6;
    const int quad = lane >> 4, ml = lane & 15;
    const int m0 = blockIdx.x*128 + wv*32;
    const int r0 = m0 + ml, r1 = m0 + 16 + ml;
    const int ga0 = vertex[r0], ga1 = vertex[r1];
    const float vm0 = vmask[r0], vm1 = vmask[r1];

    f32x4 acc[16];
    #pragma unroll
    for (int i = 0; i < 16; ++i) acc[i] = (f32x4){0.f,0.f,0.f,0.f};
    const short* wcol = WT + (size_t)ml*96;

    #pragma unroll
    for (int kc = 0; kc < 3; ++kc) {
        const int kq = kc*32 + quad*8;
        float av0[8], av1[8];
        const float* p0r = atomf + (size_t)ga0*AF + kq;
        const float* p1r = atomf + (size_t)ga1*AF + kq;
        #pragma unroll
        for (int j2 = 0; j2 < 4; ++j2) {
            int k = kq + 2*j2;
            if (k + 2 <= AF) {
                float2 v0 = *(const float2*)(p0r + 2*j2);
                float2 v1 = *(const float2*)(p1r + 2*j2);
                av0[2*j2]=v0.x*vm0; av0[2*j2+1]=v0.y*vm0;
                av1[2*j2]=v1.x*vm1; av1[2*j2+1]=v1.y*vm1;
            } else { av0[2*j2]=0.f; av0[2*j2+1]=0.f; av1[2*j2]=0.f; av1[2*j2+1]=0.f; }
        }
        bf16x8 a0h, a0l, a1h, a1l;
        #pragma unroll
        for (int j = 0; j < 8; ++j) {
            short h, l;
            split2(av0[j], h, l); a0h[j]=h; a0l[j]=l;
            split2(av1[j], h, l); a1h[j]=h; a1l[j]=l;
        }
        #pragma unroll
        for (int nt = 0; nt < 8; ++nt) {
            const short* bp = wcol + (size_t)nt*16*96 + kq;
            bf16x8 bh = *(const bf16x8*)bp;
            bf16x8 bl = *(const bf16x8*)(bp + 12288);
            MFMA3(acc[nt],   a0h, a0l, bh, bl);
            MFMA3(acc[8+nt], a1h, a1l, bh, bl);
        }
    }

    #pragma unroll
    for (int mt = 0; mt < 2; ++mt) {
        #pragma unroll
        for (int nt = 0; nt < 8; ++nt) {
            int col = nt*16 + ml;
            float bj = bias[col];
            #pragma unroll
            for (int r = 0; r < 4; ++r) {
                int gm = m0 + mt*16 + quad*4 + r;
                float v = gelu1(acc[mt*8+nt][r] + bj);
                size_t off = (size_t)gm*128 + col;
                vf[off] = v; h0[off] = v;
                short h_, l_; split2(v, h_, l_);
                vfh[off] = h_; vfl[off] = l_;
            }
        }
    }
}

// ---------------------------------------------------------------------------
// merged weight-prep kernel (all converts + transposes)
// ---------------------------------------------------------------------------
__device__ __forceinline__ void cvt_t(const float* __restrict__ src, short* __restrict__ dst,
                                      int i, int K, int Kpad, int total)
{
    int z = i / (128*Kpad); int rem = i - z*128*Kpad;
    int col = rem / Kpad; int k = rem - col*Kpad;
    float v = (k < K) ? src[(size_t)z*K*128 + (size_t)k*128 + col] : 0.f;
    short h, l; split2(v, h, l);
    dst[i] = h; dst[total + i] = l;
}

__global__ void wprep_kernel(
    const float* __restrict__ emb_w, const float* __restrict__ wvm_w,
    const float* __restrict__ u1_w, const float* __restrict__ u2_w,
    const float* __restrict__ fu_w, const float* __restrict__ wzm1_w,
    const float* __restrict__ g_wih, const float* __restrict__ g_whh,
    const float* __restrict__ gm_wih, const float* __restrict__ gm_whh,
    short* __restrict__ wt_emb, short* __restrict__ wt_wvm,
    short* __restrict__ wt_u1, short* __restrict__ wt_u2,
    short* __restrict__ wt_fu, short* __restrict__ wt_wzm1,
    short* __restrict__ wt_gih, short* __restrict__ wt_ghh,
    float* __restrict__ WTih_s, float* __restrict__ WThh_s)
{
    int i = blockIdx.x*256 + threadIdx.x;
    if (i < 12288) cvt_t(emb_w, wt_emb, i, 82, 96, 12288);
    else if (i < 208896) cvt_t(wvm_w, wt_wvm, i-12288, 128, 128, 196608);
    else if (i < 270336) cvt_t(u1_w, wt_u1, i-208896, 134, 160, 61440);
    else if (i < 368640) cvt_t(u2_w, wt_u2, i-270336, 256, 256, 98304);
    else if (i < 417792) cvt_t(fu_w, wt_fu, i-368640, 128, 128, 49152);
    else if (i < 466944) cvt_t(wzm1_w, wt_wzm1, i-417792, 128, 128, 49152);
    else if (i < 516096) { int j = i-466944; short h,l; split2(g_wih[j],h,l); wt_gih[j]=h; wt_gih[49152+j]=l; }
    else if (i < 565248) { int j = i-516096; short h,l; split2(g_whh[j],h,l); wt_ghh[j]=h; wt_ghh[49152+j]=l; }
    else if (i < 614400) { int o = i-565248; int k = o/384, j = o-k*384; WTih_s[o] = gm_wih[j*128 + k]; }
    else if (i < 663552) { int o = i-614400; int k = o/384, j = o-k*384; WThh_s[o] = gm_whh[j*128 + k]; }
}

__global__ void e_gather_kernel(const float* __restrict__ bondf, const int* __restrict__ edge,
                                short* __restrict__ eh, short* __restrict__ el)
{
    int idx = blockIdx.x*256 + threadIdx.x;
    if (idx >= BB*EE*8) return;
    int m = idx >> 3, j = idx & 7;
    float v = (j < BF) ? bondf[edge[m]*BF + j] : 0.f;
    short h, l; split2(v, h, l);
    eh[idx] = h; el[idx] = l;
}

__global__ __launch_bounds__(256) void master_init_kernel(const float* __restrict__ vf,
                                                          const float* __restrict__ vm,
                                                          float* __restrict__ master)
{
    __shared__ float red[256];
    int b = blockIdx.x; int t = threadIdx.x; int hcol = t & 127; int half = t >> 7;
    float s = 0.f;
    for (int n = half; n < NN; n += 2)
        s += vf[((size_t)b*NN + n)*HH + hcol] * vm[b*NN + n];
    red[t] = s; __syncthreads();
    if (half == 0) master[b*HH + hcol] = red[hcol] + red[hcol + 128];
}

__global__ void copy_out_kernel(const float* __restrict__ vf, const float* __restrict__ master,
                                float* __restrict__ out)
{
    int i = blockIdx.x*256 + threadIdx.x;
    const int nvf4 = SLAB/4;
    if (i < nvf4) ((float4*)out)[i] = ((const float4*)vf)[i];
    else ((float4*)out)[i] = ((const float4*)master)[i - nvf4];
}

// ---------------------------------------------------------------------------
extern "C" void kernel_launch(void* const* d_in, const int* in_sizes, int n_in,
                              void* d_out, int out_size, void* d_ws, size_t ws_size,
                              hipStream_t stream)
{
    (void)in_sizes; (void)n_in; (void)out_size; (void)ws_size;
    const float* vmask = (const float*)d_in[1];
    const int*   vertex= (const int*)d_in[2];
    const int*   edge  = (const int*)d_in[3];
    const int*   aadj  = (const int*)d_in[4];
    const int*   badj  = (const int*)d_in[5];
    const float* nbm   = (const float*)d_in[6];
    const float* atomf = (const float*)d_in[7];
    const float* bondf = (const float*)d_in[8];
    const float* emb_w = (const float*)d_in[9];
    const float* emb_b = (const float*)d_in[10];
    const float* u1_w  = (const float*)d_in[11];
    const float* u1_b  = (const float*)d_in[12];
    const float* u2_w  = (const float*)d_in[13];
    const float* u2_b  = (const float*)d_in[14];
    const float* fu_w  = (const float*)d_in[15];
    const float* fu_b  = (const float*)d_in[16];
    const float* wvm_w = (const float*)d_in[17];
    const float* wvm_b = (const float*)d_in[18];
    const float* wmain_w=(const float*)d_in[19];
    const float* wmain_b=(const float*)d_in[20];
    const float* wbmm_w= (const float*)d_in[21];
    const float* wbmm_b= (const float*)d_in[22];
    const float* khead_w=(const float*)d_in[23];
    const float* khead_b=(const float*)d_in[24];
    const float* wmaster_w=(const float*)d_in[25];
    const float* wmaster_b=(const float*)d_in[26];
    const float* wm2m_w= (const float*)d_in[27];
    const float* wm2m_b= (const float*)d_in[28];
    const float* wzm1_w= (const float*)d_in[29];
    const float* wzm1_b= (const float*)d_in[30];
    const float* wzm2_w= (const float*)d_in[31];
    const float* wzm2_b= (const float*)d_in[32];
    const float* wzs1_w= (const float*)d_in[33];
    const float* wzs1_b= (const float*)d_in[34];
    const float* wzs2_w= (const float*)d_in[35];
    const float* wzs2_b= (const float*)d_in[36];
    const float* g_wih = (const float*)d_in[37];
    const float* g_whh = (const float*)d_in[38];
    const float* g_bih = (const float*)d_in[39];
    const float* g_bhh = (const float*)d_in[40];
    const float* gm_wih= (const float*)d_in[41];
    const float* gm_whh= (const float*)d_in[42];
    const float* gm_bih= (const float*)d_in[43];
    const float* gm_bhh= (const float*)d_in[44];

    float* ws     = (float*)d_ws;
    float* vf     = ws;
    float* h0     = vf + SLAB;
    float* score  = h0 + SLAB;
    float* ctx    = score + BB*KK*NN;
    float* satt   = ctx + BB*KK*HH;
    float* master = satt + BB*KK;
    float* m2m    = master + BB*HH;
    float* t2     = m2m + BB*HH;
    float* WTih_s = t2 + BB*HH;
    float* WThh_s = WTih_s + 128*384;
    short* vfh    = (short*)(WThh_s + 128*384);
    short* vfl    = vfh + SLAB;
    short* nlh    = vfl + SLAB;
    short* nll    = nlh + SLAB;
    short* eh     = nll + SLAB;
    short* el     = eh + BB*EE*8;
    short* wt_emb   = el + BB*EE*8;
    short* wt_wvm   = wt_emb   + 2*12288;
    short* wt_u1    = wt_wvm   + 2*196608;
    short* wt_u2    = wt_u1    + 2*61440;
    short* wt_fu    = wt_u2    + 2*98304;
    short* wt_wzm1  = wt_fu    + 2*49152;
    short* wt_gih   = wt_wzm1  + 2*49152;
    short* wt_ghh   = wt_gih   + 2*49152;

    wprep_kernel<<<2592, 256, 0, stream>>>(
        emb_w, wvm_w, u1_w, u2_w, fu_w, wzm1_w, g_wih, g_whh, gm_wih, gm_whh,
        wt_emb, wt_wvm, wt_u1, wt_u2, wt_fu, wt_wzm1, wt_gih, wt_ghh,
        WTih_s, WThh_s);

    e_gather_kernel<<<(BB*EE*8 + 255)/256, 256, 0, stream>>>(bondf, edge, eh, el);

    embed_kernel<<<256, 256, 0, stream>>>(atomf, vertex, vmask, wt_emb, emb_b,
                                          vf, h0, vfh, vfl);
    master_init_kernel<<<BB, 256, 0, stream>>>(vf, vmask, master);

    for (int i = 0; i < LL; ++i) {
        float theta = logf(0.5f/(float)(i+1) + 1.f);

        mvscore_kernel<<<dim3(256,1,4), 256, 0, stream>>>(
            vfh, vfl, wt_wvm + (size_t)i*4*16384, wvm_b + (size_t)i*4*128,
            master, wbmm_w + (size_t)i*KK*HH, wbmm_b + (size_t)i*KK, score);

        attctx_kernel<<<BB*KK, 256, 0, stream>>>(score, vmask, vf, satt, ctx);

        master_fused<<<BB, 256, 0, stream>>>(
            ctx, satt, master,
            wmain_w + (size_t)i*KK*HH*HH, wmain_b + (size_t)i*KK*HH,
            khead_w + (size_t)i*KK*HH*HH, khead_b + i*HH,
            wm2m_w + (size_t)i*HH*HH, wm2m_b + i*HH,
            wmaster_w + (size_t)i*HH*HH, wmaster_b + i*HH,
            wzm2_w + (size_t)i*HH*HH, wzm2_b + i*HH,
            wzs1_w + (size_t)i*HH*HH, wzs1_b + i*HH,
            wzs2_w + (size_t)i*HH*HH, wzs2_b + i*HH,
            WTih_s, WThh_s, gm_bih, gm_bhh,
            m2m, t2);

        u1_kernel<<<2048, 256, 0, stream>>>(
            vfh, vfl, eh, el, wt_u1 + (size_t)i*128*160, u1_b + i*HH,
            aadj, badj, nbm, nlh, nll);

        vchain<<<2048, 256, 0, stream>>>(
            nlh, nll, vf, vfh, vfl, h0,
            wt_u2 + (size_t)i*128*256, u2_b + i*HH,
            wt_fu + (size_t)i*16384, fu_b + i*HH,
            wt_wzm1 + (size_t)i*16384, wzm1_b + i*HH,
            wt_gih, wt_ghh, g_bih, g_bhh,
            t2, m2m, theta);
    }

    copy_out_kernel<<<(SLAB + BB*HH)/4/256, 256, 0, stream>>>(vf, master, (float*)d_out);
}

// Round 9
// 1458.218 us; speedup vs baseline: 1.2197x; 1.0008x over previous
//
#include <hip/hip_runtime.h>
#include <hip/hip_bf16.h>
#include <cmath>

// Problem constants
#define BB 64
#define NN 512
#define NBS 8
#define EE 2048
#define HH 128
#define LL 3
#define KK 4
#define AF 82
#define BF 6
#define SLAB 4194304   // B*N*H floats

typedef __attribute__((ext_vector_type(8))) short bf16x8;
typedef __attribute__((ext_vector_type(4))) float f32x4;

__device__ __forceinline__ float gelu1(float x){ return 0.5f*x*(1.f+erff(x*0.7071067811865475f)); }
__device__ __forceinline__ float sig1(float x){ return 1.f/(1.f+expf(-x)); }
__device__ __forceinline__ short f2bs(float x){ __hip_bfloat16 b=__float2bfloat16(x); return *reinterpret_cast<short*>(&b); }
__device__ __forceinline__ float bs2f(short s){ unsigned u = ((unsigned)(unsigned short)s) << 16; union{unsigned u; float f;} c; c.u=u; return c.f; }
__device__ __forceinline__ void split2(float v, short& hi, short& lo){ hi = f2bs(v); lo = f2bs(v - bs2f(hi)); }

#define MFMA3(ACC, AH, AL, BH, BL) \
    ACC = __builtin_amdgcn_mfma_f32_16x16x32_bf16(AH, BH, ACC, 0,0,0); \
    ACC = __builtin_amdgcn_mfma_f32_16x16x32_bf16(AL, BH, ACC, 0,0,0); \
    ACC = __builtin_amdgcn_mfma_f32_16x16x32_bf16(AH, BL, ACC, 0,0,0);

// ---------------------------------------------------------------------------
// k1 fat kernel: u1 (blocks 0..2047, LDS-free) || mvscore (blocks 2048..3071)
// ---------------------------------------------------------------------------
__global__ __launch_bounds__(256) void layer_k1(
    // shared
    const short* __restrict__ vfh, const short* __restrict__ vfl,
    // u1
    const short* __restrict__ eh, const short* __restrict__ el,
    const short* __restrict__ wtu1, const float* __restrict__ u1b,
    const int* __restrict__ aadj, const int* __restrict__ badj,
    const float* __restrict__ nbm,
    short* __restrict__ nlh, short* __restrict__ nll,
    // mvscore
    const short* __restrict__ wtwvm, const float* __restrict__ wvmb,
    const float* __restrict__ master,
    const float* __restrict__ wbw, const float* __restrict__ wbb,
    float* __restrict__ score)
{
    const int bid = blockIdx.x;
    const int t = threadIdx.x;
    const int lane = t & 63, wv = t >> 6;
    const int quad = lane >> 4, ml = lane & 15;

    if (bid < 2048) {
        // ---------------- u1 ----------------
        const int m0 = bid*128 + wv*32;
        const int r0 = m0 + ml, r1 = m0 + 16 + ml;
        const int ga0 = aadj[r0], ga1 = aadj[r1];
        const int gb0 = badj[r0], gb1 = badj[r1];

        f32x4 acc[16];
        #pragma unroll
        for (int i = 0; i < 16; ++i) acc[i] = (f32x4){0.f,0.f,0.f,0.f};
        const short* wcol = wtu1 + (size_t)ml*160;

        #pragma unroll
        for (int kc = 0; kc < 5; ++kc) {
            const int kq = kc*32 + quad*8;
            bf16x8 a0h, a0l, a1h, a1l;
            if (kq < 128) {
                a0h = *(const bf16x8*)(vfh + (size_t)ga0*128 + kq);
                a0l = *(const bf16x8*)(vfl + (size_t)ga0*128 + kq);
                a1h = *(const bf16x8*)(vfh + (size_t)ga1*128 + kq);
                a1l = *(const bf16x8*)(vfl + (size_t)ga1*128 + kq);
            } else if (kq == 128) {
                a0h = *(const bf16x8*)(eh + (size_t)gb0*8);
                a0l = *(const bf16x8*)(el + (size_t)gb0*8);
                a1h = *(const bf16x8*)(eh + (size_t)gb1*8);
                a1l = *(const bf16x8*)(el + (size_t)gb1*8);
            } else {
                #pragma unroll
                for (int j = 0; j < 8; ++j) { a0h[j]=0; a0l[j]=0; a1h[j]=0; a1l[j]=0; }
            }
            #pragma unroll
            for (int nt = 0; nt < 8; ++nt) {
                const short* bp = wcol + (size_t)nt*16*160 + kq;
                bf16x8 bh = *(const bf16x8*)bp;
                bf16x8 bl = *(const bf16x8*)(bp + 61440);
                MFMA3(acc[nt],   a0h, a0l, bh, bl);
                MFMA3(acc[8+nt], a1h, a1l, bh, bl);
            }
        }
        // shuffle-based segment sum over 8 rows (gelu*nbm per element first)
        float nb0[4], nb1[4];
        #pragma unroll
        for (int r = 0; r < 4; ++r) {
            nb0[r] = nbm[m0 + quad*4 + r];
            nb1[r] = nbm[m0 + 16 + quad*4 + r];
        }
        #pragma unroll
        for (int mt = 0; mt < 2; ++mt) {
            #pragma unroll
            for (int nt = 0; nt < 8; ++nt) {
                int col = nt*16 + ml;
                float bj = u1b[col];
                float s = 0.f;
                #pragma unroll
                for (int r = 0; r < 4; ++r) {
                    float nv = mt ? nb1[r] : nb0[r];
                    s += gelu1(acc[mt*8+nt][r] + bj) * nv;
                }
                s += __shfl_xor(s, 16);   // combine quad pairs {0,1} and {2,3}
                if ((quad & 1) == 0) {
                    int seg = quad >> 1;
                    size_t orow = (size_t)(m0/8 + mt*2 + seg)*128 + col;
                    short h_, l_; split2(s, h_, l_);
                    nlh[orow] = h_; nll[orow] = l_;
                }
            }
        }
    } else {
        // ---------------- mvscore ----------------
        const int v = bid - 2048;
        const int k = v >> 8;
        const int tile = v & 255;
        const int b = tile >> 2;
        const int r0 = tile*128 + wv*32 + ml;
        const int r1 = r0 + 16;

        bf16x8 a0h[4], a0l[4], a1h[4], a1l[4];
        #pragma unroll
        for (int kc = 0; kc < 4; ++kc) {
            const int kq = kc*32 + quad*8;
            a0h[kc] = *(const bf16x8*)(vfh + (size_t)r0*128 + kq);
            a0l[kc] = *(const bf16x8*)(vfl + (size_t)r0*128 + kq);
            a1h[kc] = *(const bf16x8*)(vfh + (size_t)r1*128 + kq);
            a1l[kc] = *(const bf16x8*)(vfl + (size_t)r1*128 + kq);
        }

        f32x4 acc[16];
        #pragma unroll
        for (int i = 0; i < 16; ++i) acc[i] = (f32x4){0.f,0.f,0.f,0.f};
        const short* wcol = wtwvm + (size_t)k*16384 + (size_t)ml*128;
        #pragma unroll
        for (int kc = 0; kc < 4; ++kc) {
            const int kq = kc*32 + quad*8;
            #pragma unroll
            for (int nt = 0; nt < 8; ++nt) {
                const short* bp = wcol + (size_t)nt*16*128 + kq;
                bf16x8 bh = *(const bf16x8*)bp;
                bf16x8 bl = *(const bf16x8*)(bp + 196608);
                MFMA3(acc[nt],   a0h[kc], a0l[kc], bh, bl);
                MFMA3(acc[8+nt], a1h[kc], a1l[kc], bh, bl);
            }
        }
        float wv8[8], bj8[8];
        #pragma unroll
        for (int nt = 0; nt < 8; ++nt) {
            int col = nt*16 + ml;
            wv8[nt] = master[(size_t)b*128 + col] * wbw[(size_t)k*128 + col];
            bj8[nt] = wvmb[(size_t)k*128 + col];
        }
        float kb = wbb[k];
        #pragma unroll
        for (int mt = 0; mt < 2; ++mt) {
            #pragma unroll
            for (int r = 0; r < 4; ++r) {
                float s = 0.f;
                #pragma unroll
                for (int nt = 0; nt < 8; ++nt)
                    s += tanhf(acc[mt*8+nt][r] + bj8[nt]) * wv8[nt];
                s += __shfl_xor(s, 1); s += __shfl_xor(s, 2);
                s += __shfl_xor(s, 4); s += __shfl_xor(s, 8);
                if (ml == 0) {
                    int nloc = (tile & 3)*128 + wv*32 + mt*16 + quad*4 + r;
                    score[((size_t)(b*KK + k))*NN + nloc] = s + kb;
                }
            }
        }
    }
}

// ---------------------------------------------------------------------------
// k2 fat kernel: vchain (blocks 0..2047) || attctx (blocks 2048..2303)
// vchain reads vf_cur, writes vf_next (ping-pong) -> no race with attctx.
// ---------------------------------------------------------------------------
__global__ __launch_bounds__(256) void layer_k2(
    // vchain
    const short* __restrict__ nlh, const short* __restrict__ nll,
    const float* __restrict__ vfc, const short* __restrict__ vfch, const short* __restrict__ vfcl,
    float* __restrict__ vfn, short* __restrict__ vfnh, short* __restrict__ vfnl,
    const float* __restrict__ h0,
    const short* __restrict__ wu2, const float* __restrict__ u2b,
    const short* __restrict__ wfu, const float* __restrict__ fub,
    const short* __restrict__ wzm, const float* __restrict__ zmb,
    const short* __restrict__ wih, const short* __restrict__ whh,
    const float* __restrict__ bih, const float* __restrict__ bhh,
    const float* __restrict__ t2, const float* __restrict__ m2m,
    float theta,
    // attctx
    const float* __restrict__ score, const float* __restrict__ vm,
    float* __restrict__ satt, float* __restrict__ ctx)
{
    __shared__ __align__(16) char smem[8704];
    const int bid = blockIdx.x;
    const int t = threadIdx.x;

    if (bid < 2048) {
        short* sh = (short*)smem;
        short* sl = sh + 16*136;
        const int lane = t & 63, wv = t >> 6;
        const int quad = lane >> 4, ml = lane & 15;
        const int base = bid * 16;
        const int arow = base + ml;
        const int bb = base >> 9;
        const int c0 = wv*32 + ml;
        const int kq0 = quad*8;

        f32x4 acc0 = (f32x4){0.f,0.f,0.f,0.f}, acc1 = (f32x4){0.f,0.f,0.f,0.f};

        // stage A: hi = concat(nl, vf) @ u2
        #pragma unroll
        for (int kc = 0; kc < 8; ++kc) {
            const int kq = kc*32 + kq0;
            bf16x8 ah, al;
            if (kc < 4) {
                ah = *(const bf16x8*)(nlh + (size_t)arow*128 + kq);
                al = *(const bf16x8*)(nll + (size_t)arow*128 + kq);
            } else {
                ah = *(const bf16x8*)(vfch + (size_t)arow*128 + kq - 128);
                al = *(const bf16x8*)(vfcl + (size_t)arow*128 + kq - 128);
            }
            const short* bp0 = wu2 + (size_t)c0*256 + kq;
            const short* bp1 = wu2 + (size_t)(c0+16)*256 + kq;
            MFMA3(acc0, ah, al, *(const bf16x8*)bp0, *(const bf16x8*)(bp0+98304));
            MFMA3(acc1, ah, al, *(const bf16x8*)bp1, *(const bf16x8*)(bp1+98304));
        }
        f32x4 sup0, sup1;
        {
            float bj0 = u2b[c0], bj1 = u2b[c0+16];
            #pragma unroll
            for (int r = 0; r < 4; ++r) {
                int row = base + quad*4 + r;
                sup0[r] = 0.9f*(acc0[r] + bj0) + 0.1f*h0[(size_t)row*128 + c0];
                sup1[r] = 0.9f*(acc1[r] + bj1) + 0.1f*h0[(size_t)row*128 + c0+16];
            }
        }
        #pragma unroll
        for (int r = 0; r < 4; ++r) {
            int lrow = quad*4 + r;
            short h_, l_;
            split2(sup0[r], h_, l_); sh[lrow*136 + c0] = h_; sl[lrow*136 + c0] = l_;
            split2(sup1[r], h_, l_); sh[lrow*136 + c0+16] = h_; sl[lrow*136 + c0+16] = l_;
        }
        __syncthreads();

        // stage B: sv
        acc0 = (f32x4){0.f,0.f,0.f,0.f}; acc1 = (f32x4){0.f,0.f,0.f,0.f};
        #pragma unroll
        for (int kc = 0; kc < 4; ++kc) {
            const int kq = kc*32 + kq0;
            bf16x8 xh = *(const bf16x8*)&sh[ml*136 + kq];
            bf16x8 xl = *(const bf16x8*)&sl[ml*136 + kq];
            const short* bp0 = wfu + (size_t)c0*128 + kq;
            const short* bp1 = wfu + (size_t)(c0+16)*128 + kq;
            MFMA3(acc0, xh, xl, *(const bf16x8*)bp0, *(const bf16x8*)(bp0+49152));
            MFMA3(acc1, xh, xl, *(const bf16x8*)bp1, *(const bf16x8*)(bp1+49152));
        }
        f32x4 sv0, sv1;
        {
            float bj0 = fub[c0], bj1 = fub[c0+16];
            #pragma unroll
            for (int r = 0; r < 4; ++r) {
                sv0[r] = theta*(acc0[r] + bj0) + (1.f-theta)*sup0[r];
                sv1[r] = theta*(acc1[r] + bj1) + (1.f-theta)*sup1[r];
            }
        }
        __syncthreads();
        #pragma unroll
        for (int r = 0; r < 4; ++r) {
            int lrow = quad*4 + r;
            short h_, l_;
            split2(sv0[r], h_, l_); sh[lrow*136 + c0] = h_; sl[lrow*136 + c0] = l_;
            split2(sv1[r], h_, l_); sh[lrow*136 + c0+16] = h_; sl[lrow*136 + c0+16] = l_;
        }
        __syncthreads();

        // stage C: z-gate
        acc0 = (f32x4){0.f,0.f,0.f,0.f}; acc1 = (f32x4){0.f,0.f,0.f,0.f};
        #pragma unroll
        for (int kc = 0; kc < 4; ++kc) {
            const int kq = kc*32 + kq0;
            bf16x8 xh = *(const bf16x8*)&sh[ml*136 + kq];
            bf16x8 xl = *(const bf16x8*)&sl[ml*136 + kq];
            const short* bp0 = wzm + (size_t)c0*128 + kq;
            const short* bp1 = wzm + (size_t)(c0+16)*128 + kq;
            MFMA3(acc0, xh, xl, *(const bf16x8*)bp0, *(const bf16x8*)(bp0+49152));
            MFMA3(acc1, xh, xl, *(const bf16x8*)bp1, *(const bf16x8*)(bp1+49152));
        }
        f32x4 hid0, hid1;
        {
            float bj0 = zmb[c0], bj1 = zmb[c0+16];
            float t20 = t2[(size_t)bb*128 + c0], t21 = t2[(size_t)bb*128 + c0+16];
            float m20 = m2m[(size_t)bb*128 + c0], m21 = m2m[(size_t)bb*128 + c0+16];
            #pragma unroll
            for (int r = 0; r < 4; ++r) {
                float z0 = sig1(acc0[r] + bj0 + t20);
                float z1 = sig1(acc1[r] + bj1 + t21);
                hid0[r] = (1.f-z0)*sv0[r] + z0*m20;
                hid1[r] = (1.f-z1)*sv1[r] + z1*m21;
            }
        }
        __syncthreads();
        #pragma unroll
        for (int r = 0; r < 4; ++r) {
            int lrow = quad*4 + r;
            short h_, l_;
            split2(hid0[r], h_, l_); sh[lrow*136 + c0] = h_; sl[lrow*136 + c0] = l_;
            split2(hid1[r], h_, l_); sh[lrow*136 + c0+16] = h_; sl[lrow*136 + c0+16] = l_;
        }
        __syncthreads();

        // stage D: GRU
        bf16x8 xfh[4], xfl[4], vh_[4], vl_[4];
        #pragma unroll
        for (int kc = 0; kc < 4; ++kc) {
            const int kq = kc*32 + kq0;
            xfh[kc] = *(const bf16x8*)&sh[ml*136 + kq];
            xfl[kc] = *(const bf16x8*)&sl[ml*136 + kq];
            vh_[kc] = *(const bf16x8*)(vfch + (size_t)arow*128 + kq);
            vl_[kc] = *(const bf16x8*)(vfcl + (size_t)arow*128 + kq);
        }
        f32x4 rg0, rg1, zg0, zg1;
        #pragma unroll
        for (int g = 0; g < 3; ++g) {
            f32x4 gi0 = (f32x4){0.f,0.f,0.f,0.f}, gi1 = (f32x4){0.f,0.f,0.f,0.f};
            f32x4 gh0 = (f32x4){0.f,0.f,0.f,0.f}, gh1 = (f32x4){0.f,0.f,0.f,0.f};
            #pragma unroll
            for (int kc = 0; kc < 4; ++kc) {
                const int kq = kc*32 + kq0;
                const size_t w0 = (size_t)(g*128 + c0)*128 + kq;
                const size_t w1 = (size_t)(g*128 + c0+16)*128 + kq;
                MFMA3(gi0, xfh[kc], xfl[kc], *(const bf16x8*)(wih+w0), *(const bf16x8*)(wih+w0+49152));
                MFMA3(gi1, xfh[kc], xfl[kc], *(const bf16x8*)(wih+w1), *(const bf16x8*)(wih+w1+49152));
                MFMA3(gh0, vh_[kc], vl_[kc], *(const bf16x8*)(whh+w0), *(const bf16x8*)(whh+w0+49152));
                MFMA3(gh1, vh_[kc], vl_[kc], *(const bf16x8*)(whh+w1), *(const bf16x8*)(whh+w1+49152));
            }
            if (g == 0) {
                float b10 = bih[c0], b20 = bhh[c0], b11 = bih[c0+16], b21 = bhh[c0+16];
                #pragma unroll
                for (int r = 0; r < 4; ++r) {
                    rg0[r] = sig1(gi0[r] + b10 + gh0[r] + b20);
                    rg1[r] = sig1(gi1[r] + b11 + gh1[r] + b21);
                }
            } else if (g == 1) {
                float b10 = bih[128+c0], b20 = bhh[128+c0], b11 = bih[128+c0+16], b21 = bhh[128+c0+16];
                #pragma unroll
                for (int r = 0; r < 4; ++r) {
                    zg0[r] = sig1(gi0[r] + b10 + gh0[r] + b20);
                    zg1[r] = sig1(gi1[r] + b11 + gh1[r] + b21);
                }
            } else {
                float b10 = bih[256+c0], b20 = bhh[256+c0], b11 = bih[256+c0+16], b21 = bhh[256+c0+16];
                #pragma unroll
                for (int r = 0; r < 4; ++r) {
                    int row = base + quad*4 + r;
                    size_t off0 = (size_t)row*128 + c0;
                    size_t off1 = off0 + 16;
                    float n0 = tanhf(gi0[r] + b10 + rg0[r]*(gh0[r] + b20));
                    float n1 = tanhf(gi1[r] + b11 + rg1[r]*(gh1[r] + b21));
                    float o0 = (1.f-zg0[r])*n0 + zg0[r]*vfc[off0];
                    float o1 = (1.f-zg1[r])*n1 + zg1[r]*vfc[off1];
                    vfn[off0] = o0; vfn[off1] = o1;
                    short h_, l_;
                    split2(o0, h_, l_); vfnh[off0] = h_; vfnl[off0] = l_;
                    split2(o1, h_, l_); vfnh[off1] = h_; vfnl[off1] = l_;
                }
            }
        }
    } else {
        // ---------------- attctx ----------------
        float* red = (float*)smem;       // 256
        float* att = red + 256;          // 512
        const int bk = bid - 2048, b = bk >> 2;
        float v0 = score[(size_t)bk*NN + t], v1 = score[(size_t)bk*NN + 256 + t];
        red[t] = fmaxf(v0, v1); __syncthreads();
        for (int s = 128; s; s >>= 1) { if (t < s) red[t] = fmaxf(red[t], red[t+s]); __syncthreads(); }
        float mx = red[0]; __syncthreads();
        float e0 = expf(v0 - mx) * vm[b*NN + t];
        float e1 = expf(v1 - mx) * vm[b*NN + t + 256];
        red[t] = e0 + e1; __syncthreads();
        for (int s = 128; s; s >>= 1) { if (t < s) red[t] += red[t+s]; __syncthreads(); }
        float sum = red[0];
        float inv = 1.f / (sum + 1e-6f);
        att[t] = e0*inv; att[t+256] = e1*inv;
        if (t == 0) satt[bk] = sum*inv;
        __syncthreads();
        const int d = t & 127, h = t >> 7;
        float acc = 0.f;
        const float* V = vfc + (size_t)b*NN*HH;
        #pragma unroll 8
        for (int n = h*256; n < h*256 + 256; ++n) acc += att[n]*V[(size_t)n*HH + d];
        red[t] = acc; __syncthreads();
        if (t < 128) ctx[(size_t)bk*HH + t] = red[t] + red[t+128];
    }
}

// ---------------------------------------------------------------------------
// master_fused2: kmm, mtm, mself, ts1, ts2, hsup, master GRU -> master_{i+1};
// then m2m/t2 for the NEXT layer. grid = 64 blocks.
// ---------------------------------------------------------------------------
__global__ __launch_bounds__(256) void master_fused2(
    const float* __restrict__ ctx, const float* __restrict__ satt,
    float* __restrict__ master,
    const float* __restrict__ wmain_w, const float* __restrict__ wmain_b,
    const float* __restrict__ khead_w, const float* __restrict__ khead_b,
    const float* __restrict__ wmaster_w, const float* __restrict__ wmaster_b,
    const float* __restrict__ wzs1_w,  const float* __restrict__ wzs1_b,
    const float* __restrict__ wzs2_w,  const float* __restrict__ wzs2_b,
    const float* __restrict__ WTih, const float* __restrict__ WThh,
    const float* __restrict__ bih, const float* __restrict__ bhh,
    const float* __restrict__ wm2m_n_w, const float* __restrict__ wm2m_n_b,
    const float* __restrict__ wzm2_n_w, const float* __restrict__ wzm2_n_b,
    float* __restrict__ m2m_out, float* __restrict__ t2_out)
{
    __shared__ float xs[512], ms[128], msN[128];
    __shared__ float v_mtm[128], v_mself[128], v_m2m[128], v_t2[128];
    __shared__ float v_ts1[128], v_ts2[128], v_hsup[128];
    __shared__ float gi[384], gh2[384];
    __shared__ float red[256];
    const int t = threadIdx.x;
    const int b = blockIdx.x;

    if (t < 128) ms[t] = master[(size_t)b*128 + t];
    __syncthreads();

    const int c = t & 127, p = t >> 7;

    #pragma unroll
    for (int k = 0; k < 4; ++k) {
        const float* cx = ctx + ((size_t)b*KK + k)*128;
        const float* Wk = wmain_w + (size_t)k*16384;
        float s = 0.f;
        for (int d = p*64; d < p*64+64; ++d) s += cx[d]*Wk[(size_t)d*128 + c];
        red[t] = s; __syncthreads();
        if (t < 128) xs[k*128 + c] = red[c] + red[c+128] + satt[(size_t)b*KK + k]*wmain_b[k*128 + c];
        __syncthreads();
    }

    auto matvec = [&](const float* src, const float* __restrict__ W,
                      const float* __restrict__ bias, int K, float* out, int act) {
        int half = K >> 1;
        int k0 = p*half, k1 = k0 + half;
        float s = 0.f;
        for (int k = k0; k < k1; ++k) s += src[k]*W[(size_t)k*128 + c];
        red[t] = s; __syncthreads();
        if (t < 128) {
            float v = red[c] + red[c+128] + bias[c];
            if (act == 1) v = gelu1(v); else if (act == 2) v = tanhf(v);
            out[c] = v;
        }
        __syncthreads();
    };

    matvec(xs, khead_w, khead_b, 512, v_mtm, 2);
    matvec(ms, wmaster_w, wmaster_b, 128, v_mself, 1);
    matvec(v_mself, wzs1_w, wzs1_b, 128, v_ts1, 0);
    matvec(v_mtm, wzs2_w, wzs2_b, 128, v_ts2, 0);

    if (t < 128) {
        float z = sig1(v_ts1[t] + v_ts2[t]);
        v_hsup[t] = (1.f-z)*v_mself[t] + z*v_mtm[t];
    }
    __syncthreads();

    for (int j = t; j < 384; j += 256) {
        float a = 0.f, h2 = 0.f;
        for (int k = 0; k < 128; ++k) {
            a  += v_hsup[k]*WTih[(size_t)k*384 + j];
            h2 += ms[k]*WThh[(size_t)k*384 + j];
        }
        gi[j] = a + bih[j];
        gh2[j] = h2 + bhh[j];
    }
    __syncthreads();
    if (t < 128) {
        float r = sig1(gi[t] + gh2[t]);
        float z = sig1(gi[128+t] + gh2[128+t]);
        float n = tanhf(gi[256+t] + r*gh2[256+t]);
        float nm = (1.f-z)*n + z*ms[t];
        master[(size_t)b*128 + t] = nm;
        msN[t] = nm;
    }
    __syncthreads();

    // next-layer m2m / t2
    matvec(msN, wm2m_n_w, wm2m_n_b, 128, v_m2m, 1);
    matvec(v_m2m, wzm2_n_w, wzm2_n_b, 128, v_t2, 0);
    if (t < 128) {
        m2m_out[(size_t)b*128 + t] = v_m2m[t];
        t2_out[(size_t)b*128 + t]  = v_t2[t];
    }
}

// ---------------------------------------------------------------------------
// embed: vf = gelu((atomf[vertex]*vm)@emb + b); dual-store h0 + bf16 planes.
// ---------------------------------------------------------------------------
__global__ __launch_bounds__(256) void embed_kernel(
    const float* __restrict__ atomf, const int* __restrict__ vertex,
    const float* __restrict__ vmask,
    const short* __restrict__ WT, const float* __restrict__ bias,
    float* __restrict__ vf, float* __restrict__ h0,
    short* __restrict__ vfh, short* __restrict__ vfl)
{
    const int t = threadIdx.x;
    const int lane = t & 63, wv = t >> 6;
    const int quad = lane >> 4, ml = lane & 15;
    const int m0 = blockIdx.x*128 + wv*32;
    const int r0 = m0 + ml, r1 = m0 + 16 + ml;
    const int ga0 = vertex[r0], ga1 = vertex[r1];
    const float vm0 = vmask[r0], vm1 = vmask[r1];

    f32x4 acc[16];
    #pragma unroll
    for (int i = 0; i < 16; ++i) acc[i] = (f32x4){0.f,0.f,0.f,0.f};
    const short* wcol = WT + (size_t)ml*96;

    #pragma unroll
    for (int kc = 0; kc < 3; ++kc) {
        const int kq = kc*32 + quad*8;
        float av0[8], av1[8];
        const float* p0r = atomf + (size_t)ga0*AF + kq;
        const float* p1r = atomf + (size_t)ga1*AF + kq;
        #pragma unroll
        for (int j2 = 0; j2 < 4; ++j2) {
            int k = kq + 2*j2;
            if (k + 2 <= AF) {
                float2 v0 = *(const float2*)(p0r + 2*j2);
                float2 v1 = *(const float2*)(p1r + 2*j2);
                av0[2*j2]=v0.x*vm0; av0[2*j2+1]=v0.y*vm0;
                av1[2*j2]=v1.x*vm1; av1[2*j2+1]=v1.y*vm1;
            } else { av0[2*j2]=0.f; av0[2*j2+1]=0.f; av1[2*j2]=0.f; av1[2*j2+1]=0.f; }
        }
        bf16x8 a0h, a0l, a1h, a1l;
        #pragma unroll
        for (int j = 0; j < 8; ++j) {
            short h, l;
            split2(av0[j], h, l); a0h[j]=h; a0l[j]=l;
            split2(av1[j], h, l); a1h[j]=h; a1l[j]=l;
        }
        #pragma unroll
        for (int nt = 0; nt < 8; ++nt) {
            const short* bp = wcol + (size_t)nt*16*96 + kq;
            bf16x8 bh = *(const bf16x8*)bp;
            bf16x8 bl = *(const bf16x8*)(bp + 12288);
            MFMA3(acc[nt],   a0h, a0l, bh, bl);
            MFMA3(acc[8+nt], a1h, a1l, bh, bl);
        }
    }

    #pragma unroll
    for (int mt = 0; mt < 2; ++mt) {
        #pragma unroll
        for (int nt = 0; nt < 8; ++nt) {
            int col = nt*16 + ml;
            float bj = bias[col];
            #pragma unroll
            for (int r = 0; r < 4; ++r) {
                int gm = m0 + mt*16 + quad*4 + r;
                float v = gelu1(acc[mt*8+nt][r] + bj);
                size_t off = (size_t)gm*128 + col;
                vf[off] = v; h0[off] = v;
                short h_, l_; split2(v, h_, l_);
                vfh[off] = h_; vfl[off] = l_;
            }
        }
    }
}

// ---------------------------------------------------------------------------
// master_init2: master = sum(vf*vm) + m2m_0/t2_0
// ---------------------------------------------------------------------------
__global__ __launch_bounds__(256) void master_init2(
    const float* __restrict__ vf, const float* __restrict__ vm,
    const float* __restrict__ wm2m_w, const float* __restrict__ wm2m_b,
    const float* __restrict__ wzm2_w, const float* __restrict__ wzm2_b,
    float* __restrict__ master, float* __restrict__ m2m_out, float* __restrict__ t2_out)
{
    __shared__ float red[256], ms[128], v_m2m[128];
    const int b = blockIdx.x, t = threadIdx.x;
    const int hcol = t & 127, half = t >> 7;
    float s = 0.f;
    for (int n = half; n < NN; n += 2)
        s += vf[((size_t)b*NN + n)*HH + hcol] * vm[b*NN + n];
    red[t] = s; __syncthreads();
    if (half == 0) { float v = red[hcol] + red[hcol+128]; ms[hcol] = v; master[(size_t)b*HH + hcol] = v; }
    __syncthreads();
    const int c = t & 127, p = t >> 7;
    {
        float s2 = 0.f;
        for (int k = p*64; k < p*64+64; ++k) s2 += ms[k]*wm2m_w[(size_t)k*128 + c];
        red[t] = s2; __syncthreads();
        if (t < 128) { float v = gelu1(red[c] + red[c+128] + wm2m_b[c]); v_m2m[c] = v; m2m_out[(size_t)b*128 + c] = v; }
        __syncthreads();
    }
    {
        float s2 = 0.f;
        for (int k = p*64; k < p*64+64; ++k) s2 += v_m2m[k]*wzm2_w[(size_t)k*128 + c];
        red[t] = s2; __syncthreads();
        if (t < 128) t2_out[(size_t)b*128 + c] = red[c] + red[c+128] + wzm2_b[c];
    }
}

// ---------------------------------------------------------------------------
// setup kernels
// ---------------------------------------------------------------------------
__device__ __forceinline__ void cvt_t(const float* __restrict__ src, short* __restrict__ dst,
                                      int i, int K, int Kpad, int total)
{
    int z = i / (128*Kpad); int rem = i - z*128*Kpad;
    int col = rem / Kpad; int k = rem - col*Kpad;
    float v = (k < K) ? src[(size_t)z*K*128 + (size_t)k*128 + col] : 0.f;
    short h, l; split2(v, h, l);
    dst[i] = h; dst[total + i] = l;
}

__global__ void wprep_kernel(
    const float* __restrict__ emb_w, const float* __restrict__ wvm_w,
    const float* __restrict__ u1_w, const float* __restrict__ u2_w,
    const float* __restrict__ fu_w, const float* __restrict__ wzm1_w,
    const float* __restrict__ g_wih, const float* __restrict__ g_whh,
    const float* __restrict__ gm_wih, const float* __restrict__ gm_whh,
    short* __restrict__ wt_emb, short* __restrict__ wt_wvm,
    short* __restrict__ wt_u1, short* __restrict__ wt_u2,
    short* __restrict__ wt_fu, short* __restrict__ wt_wzm1,
    short* __restrict__ wt_gih, short* __restrict__ wt_ghh,
    float* __restrict__ WTih_s, float* __restrict__ WThh_s)
{
    int i = blockIdx.x*256 + threadIdx.x;
    if (i < 12288) cvt_t(emb_w, wt_emb, i, 82, 96, 12288);
    else if (i < 208896) cvt_t(wvm_w, wt_wvm, i-12288, 128, 128, 196608);
    else if (i < 270336) cvt_t(u1_w, wt_u1, i-208896, 134, 160, 61440);
    else if (i < 368640) cvt_t(u2_w, wt_u2, i-270336, 256, 256, 98304);
    else if (i < 417792) cvt_t(fu_w, wt_fu, i-368640, 128, 128, 49152);
    else if (i < 466944) cvt_t(wzm1_w, wt_wzm1, i-417792, 128, 128, 49152);
    else if (i < 516096) { int j = i-466944; short h,l; split2(g_wih[j],h,l); wt_gih[j]=h; wt_gih[49152+j]=l; }
    else if (i < 565248) { int j = i-516096; short h,l; split2(g_whh[j],h,l); wt_ghh[j]=h; wt_ghh[49152+j]=l; }
    else if (i < 614400) { int o = i-565248; int k = o/384, j = o-k*384; WTih_s[o] = gm_wih[j*128 + k]; }
    else if (i < 663552) { int o = i-614400; int k = o/384, j = o-k*384; WThh_s[o] = gm_whh[j*128 + k]; }
}

__global__ void e_gather_kernel(const float* __restrict__ bondf, const int* __restrict__ edge,
                                short* __restrict__ eh, short* __restrict__ el)
{
    int idx = blockIdx.x*256 + threadIdx.x;
    if (idx >= BB*EE*8) return;
    int m = idx >> 3, j = idx & 7;
    float v = (j < BF) ? bondf[edge[m]*BF + j] : 0.f;
    short h, l; split2(v, h, l);
    eh[idx] = h; el[idx] = l;
}

__global__ void copy_out_kernel(const float* __restrict__ vf, const float* __restrict__ master,
                                float* __restrict__ out)
{
    int i = blockIdx.x*256 + threadIdx.x;
    const int nvf4 = SLAB/4;
    if (i < nvf4) ((float4*)out)[i] = ((const float4*)vf)[i];
    else ((float4*)out)[i] = ((const float4*)master)[i - nvf4];
}

// ---------------------------------------------------------------------------
extern "C" void kernel_launch(void* const* d_in, const int* in_sizes, int n_in,
                              void* d_out, int out_size, void* d_ws, size_t ws_size,
                              hipStream_t stream)
{
    (void)in_sizes; (void)n_in; (void)out_size; (void)ws_size;
    const float* vmask = (const float*)d_in[1];
    const int*   vertex= (const int*)d_in[2];
    const int*   edge  = (const int*)d_in[3];
    const int*   aadj  = (const int*)d_in[4];
    const int*   badj  = (const int*)d_in[5];
    const float* nbm   = (const float*)d_in[6];
    const float* atomf = (const float*)d_in[7];
    const float* bondf = (const float*)d_in[8];
    const float* emb_w = (const float*)d_in[9];
    const float* emb_b = (const float*)d_in[10];
    const float* u1_w  = (const float*)d_in[11];
    const float* u1_b  = (const float*)d_in[12];
    const float* u2_w  = (const float*)d_in[13];
    const float* u2_b  = (const float*)d_in[14];
    const float* fu_w  = (const float*)d_in[15];
    const float* fu_b  = (const float*)d_in[16];
    const float* wvm_w = (const float*)d_in[17];
    const float* wvm_b = (const float*)d_in[18];
    const float* wmain_w=(const float*)d_in[19];
    const float* wmain_b=(const float*)d_in[20];
    const float* wbmm_w= (const float*)d_in[21];
    const float* wbmm_b= (const float*)d_in[22];
    const float* khead_w=(const float*)d_in[23];
    const float* khead_b=(const float*)d_in[24];
    const float* wmaster_w=(const float*)d_in[25];
    const float* wmaster_b=(const float*)d_in[26];
    const float* wm2m_w= (const float*)d_in[27];
    const float* wm2m_b= (const float*)d_in[28];
    const float* wzm1_w= (const float*)d_in[29];
    const float* wzm1_b= (const float*)d_in[30];
    const float* wzm2_w= (const float*)d_in[31];
    const float* wzm2_b= (const float*)d_in[32];
    const float* wzs1_w= (const float*)d_in[33];
    const float* wzs1_b= (const float*)d_in[34];
    const float* wzs2_w= (const float*)d_in[35];
    const float* wzs2_b= (const float*)d_in[36];
    const float* g_wih = (const float*)d_in[37];
    const float* g_whh = (const float*)d_in[38];
    const float* g_bih = (const float*)d_in[39];
    const float* g_bhh = (const float*)d_in[40];
    const float* gm_wih= (const float*)d_in[41];
    const float* gm_whh= (const float*)d_in[42];
    const float* gm_bih= (const float*)d_in[43];
    const float* gm_bhh= (const float*)d_in[44];

    float* ws     = (float*)d_ws;
    float* vfA    = ws;
    float* vfB    = vfA + SLAB;
    float* h0     = vfB + SLAB;
    float* score  = h0 + SLAB;
    float* ctx    = score + BB*KK*NN;
    float* satt   = ctx + BB*KK*HH;
    float* master = satt + BB*KK;
    float* m2m    = master + BB*HH;
    float* t2     = m2m + BB*HH;
    float* WTih_s = t2 + BB*HH;
    float* WThh_s = WTih_s + 128*384;
    short* vfhA   = (short*)(WThh_s + 128*384);
    short* vflA   = vfhA + SLAB;
    short* vfhB   = vflA + SLAB;
    short* vflB   = vfhB + SLAB;
    short* nlh    = vflB + SLAB;
    short* nll    = nlh + SLAB;
    short* eh     = nll + SLAB;
    short* el     = eh + BB*EE*8;
    short* wt_emb   = el + BB*EE*8;
    short* wt_wvm   = wt_emb   + 2*12288;
    short* wt_u1    = wt_wvm   + 2*196608;
    short* wt_u2    = wt_u1    + 2*61440;
    short* wt_fu    = wt_u2    + 2*98304;
    short* wt_wzm1  = wt_fu    + 2*49152;
    short* wt_gih   = wt_wzm1  + 2*49152;
    short* wt_ghh   = wt_gih   + 2*49152;

    wprep_kernel<<<2592, 256, 0, stream>>>(
        emb_w, wvm_w, u1_w, u2_w, fu_w, wzm1_w, g_wih, g_whh, gm_wih, gm_whh,
        wt_emb, wt_wvm, wt_u1, wt_u2, wt_fu, wt_wzm1, wt_gih, wt_ghh,
        WTih_s, WThh_s);

    e_gather_kernel<<<(BB*EE*8 + 255)/256, 256, 0, stream>>>(bondf, edge, eh, el);

    embed_kernel<<<256, 256, 0, stream>>>(atomf, vertex, vmask, wt_emb, emb_b,
                                          vfA, h0, vfhA, vflA);

    master_init2<<<BB, 256, 0, stream>>>(vfA, vmask, wm2m_w, wm2m_b, wzm2_w, wzm2_b,
                                         master, m2m, t2);

    for (int i = 0; i < LL; ++i) {
        float theta = logf(0.5f/(float)(i+1) + 1.f);
        const bool even = (i % 2 == 0);
        float* vfc  = even ? vfA  : vfB;
        short* vfch = even ? vfhA : vfhB;
        short* vfcl = even ? vflA : vflB;
        float* vfn  = even ? vfB  : vfA;
        short* vfnh = even ? vfhB : vfhA;
        short* vfnl = even ? vflB : vflA;
        int nx = (i+1 < LL) ? i+1 : i;

        layer_k1<<<3072, 256, 0, stream>>>(
            vfch, vfcl,
            eh, el, wt_u1 + (size_t)i*128*160, u1_b + i*HH, aadj, badj, nbm, nlh, nll,
            wt_wvm + (size_t)i*4*16384, wvm_b + (size_t)i*4*128,
            master, wbmm_w + (size_t)i*KK*HH, wbmm_b + (size_t)i*KK, score);

        layer_k2<<<2304, 256, 0, stream>>>(
            nlh, nll, vfc, vfch, vfcl, vfn, vfnh, vfnl, h0,
            wt_u2 + (size_t)i*128*256, u2_b + i*HH,
            wt_fu + (size_t)i*16384, fu_b + i*HH,
            wt_wzm1 + (size_t)i*16384, wzm1_b + i*HH,
            wt_gih, wt_ghh, g_bih, g_bhh,
            t2, m2m, theta,
            score, vmask, satt, ctx);

        master_fused2<<<BB, 256, 0, stream>>>(
            ctx, satt, master,
            wmain_w + (size_t)i*KK*HH*HH, wmain_b + (size_t)i*KK*HH,
            khead_w + (size_t)i*KK*HH*HH, khead_b + i*HH,
            wmaster_w + (size_t)i*HH*HH, wmaster_b + i*HH,
            wzs1_w + (size_t)i*HH*HH, wzs1_b + i*HH,
            wzs2_w + (size_t)i*HH*HH, wzs2_b + i*HH,
            WTih_s, WThh_s, gm_bih, gm_bhh,
            wm2m_w + (size_t)nx*HH*HH, wm2m_b + nx*HH,
            wzm2_w + (size_t)nx*HH*HH, wzm2_b + nx*HH,
            m2m, t2);
    }

    copy_out_kernel<<<(SLAB + BB*HH)/4/256, 256, 0, stream>>>(vfB, master, (float*)d_out);
}

// Round 10
// 1208.023 us; speedup vs baseline: 1.4723x; 1.2071x over previous
//
#include <hip/hip_runtime.h>
#include <hip/hip_bf16.h>
#include <cmath>

// Problem constants
#define BB 64
#define NN 512
#define NBS 8
#define EE 2048
#define HH 128
#define LL 3
#define KK 4
#define AF 82
#define BF 6
#define SLAB 4194304   // B*N*H floats

typedef __attribute__((ext_vector_type(8))) short bf16x8;
typedef __attribute__((ext_vector_type(4))) float f32x4;

__device__ __forceinline__ float gelu1(float x){ return 0.5f*x*(1.f+erff(x*0.7071067811865475f)); }
__device__ __forceinline__ float sig1(float x){ return 1.f/(1.f+expf(-x)); }
__device__ __forceinline__ short f2bs(float x){ __hip_bfloat16 b=__float2bfloat16(x); return *reinterpret_cast<short*>(&b); }
__device__ __forceinline__ float bs2f(short s){ unsigned u = ((unsigned)(unsigned short)s) << 16; union{unsigned u; float f;} c; c.u=u; return c.f; }
__device__ __forceinline__ void split2(float v, short& hi, short& lo){ hi = f2bs(v); lo = f2bs(v - bs2f(hi)); }

#define MFMA3(ACC, AH, AL, BH, BL) \
    ACC = __builtin_amdgcn_mfma_f32_16x16x32_bf16(AH, BH, ACC, 0,0,0); \
    ACC = __builtin_amdgcn_mfma_f32_16x16x32_bf16(AL, BH, ACC, 0,0,0); \
    ACC = __builtin_amdgcn_mfma_f32_16x16x32_bf16(AH, BL, ACC, 0,0,0);

// ---------------------------------------------------------------------------
// k1 fat: pvf dense GEMM (blocks 0..255) || mvscore (blocks 256..1279)
// pvf = vf @ u1_w[:128]  -> single-bf16 pvfb (bias folded into pet)
// ---------------------------------------------------------------------------
__global__ __launch_bounds__(256) void layer_k1(
    const short* __restrict__ vfh, const short* __restrict__ vfl,
    const short* __restrict__ wtpv, short* __restrict__ pvfb,
    const short* __restrict__ wtwvm, const float* __restrict__ wvmb,
    const float* __restrict__ master,
    const float* __restrict__ wbw, const float* __restrict__ wbb,
    float* __restrict__ score)
{
    const int bid = blockIdx.x;
    const int t = threadIdx.x;
    const int lane = t & 63, wv = t >> 6;
    const int quad = lane >> 4, ml = lane & 15;

    if (bid < 256) {
        // ---------------- pvf ----------------
        const int m0 = bid*128 + wv*32;
        const int r0 = m0 + ml, r1 = r0 + 16;

        bf16x8 a0h[4], a0l[4], a1h[4], a1l[4];
        #pragma unroll
        for (int kc = 0; kc < 4; ++kc) {
            const int kq = kc*32 + quad*8;
            a0h[kc] = *(const bf16x8*)(vfh + (size_t)r0*128 + kq);
            a0l[kc] = *(const bf16x8*)(vfl + (size_t)r0*128 + kq);
            a1h[kc] = *(const bf16x8*)(vfh + (size_t)r1*128 + kq);
            a1l[kc] = *(const bf16x8*)(vfl + (size_t)r1*128 + kq);
        }
        f32x4 acc[16];
        #pragma unroll
        for (int i = 0; i < 16; ++i) acc[i] = (f32x4){0.f,0.f,0.f,0.f};
        const short* wcol = wtpv + (size_t)ml*128;
        #pragma unroll
        for (int kc = 0; kc < 4; ++kc) {
            const int kq = kc*32 + quad*8;
            #pragma unroll
            for (int nt = 0; nt < 8; ++nt) {
                const short* bp = wcol + (size_t)nt*16*128 + kq;
                bf16x8 bh = *(const bf16x8*)bp;
                bf16x8 bl = *(const bf16x8*)(bp + 49152);
                MFMA3(acc[nt],   a0h[kc], a0l[kc], bh, bl);
                MFMA3(acc[8+nt], a1h[kc], a1l[kc], bh, bl);
            }
        }
        #pragma unroll
        for (int mt = 0; mt < 2; ++mt)
            #pragma unroll
            for (int nt = 0; nt < 8; ++nt) {
                int col = nt*16 + ml;
                #pragma unroll
                for (int r = 0; r < 4; ++r) {
                    int gm = m0 + mt*16 + quad*4 + r;
                    pvfb[(size_t)gm*128 + col] = f2bs(acc[mt*8+nt][r]);
                }
            }
    } else {
        // ---------------- mvscore ----------------
        const int v = bid - 256;
        const int k = v >> 8;
        const int tile = v & 255;
        const int b = tile >> 2;
        const int r0 = tile*128 + wv*32 + ml;
        const int r1 = r0 + 16;

        bf16x8 a0h[4], a0l[4], a1h[4], a1l[4];
        #pragma unroll
        for (int kc = 0; kc < 4; ++kc) {
            const int kq = kc*32 + quad*8;
            a0h[kc] = *(const bf16x8*)(vfh + (size_t)r0*128 + kq);
            a0l[kc] = *(const bf16x8*)(vfl + (size_t)r0*128 + kq);
            a1h[kc] = *(const bf16x8*)(vfh + (size_t)r1*128 + kq);
            a1l[kc] = *(const bf16x8*)(vfl + (size_t)r1*128 + kq);
        }
        f32x4 acc[16];
        #pragma unroll
        for (int i = 0; i < 16; ++i) acc[i] = (f32x4){0.f,0.f,0.f,0.f};
        const short* wcol = wtwvm + (size_t)k*16384 + (size_t)ml*128;
        #pragma unroll
        for (int kc = 0; kc < 4; ++kc) {
            const int kq = kc*32 + quad*8;
            #pragma unroll
            for (int nt = 0; nt < 8; ++nt) {
                const short* bp = wcol + (size_t)nt*16*128 + kq;
                bf16x8 bh = *(const bf16x8*)bp;
                bf16x8 bl = *(const bf16x8*)(bp + 196608);
                MFMA3(acc[nt],   a0h[kc], a0l[kc], bh, bl);
                MFMA3(acc[8+nt], a1h[kc], a1l[kc], bh, bl);
            }
        }
        float wv8[8], bj8[8];
        #pragma unroll
        for (int nt = 0; nt < 8; ++nt) {
            int col = nt*16 + ml;
            wv8[nt] = master[(size_t)b*128 + col] * wbw[(size_t)k*128 + col];
            bj8[nt] = wvmb[(size_t)k*128 + col];
        }
        float kb = wbb[k];
        #pragma unroll
        for (int mt = 0; mt < 2; ++mt) {
            #pragma unroll
            for (int r = 0; r < 4; ++r) {
                float s = 0.f;
                #pragma unroll
                for (int nt = 0; nt < 8; ++nt)
                    s += tanhf(acc[mt*8+nt][r] + bj8[nt]) * wv8[nt];
                s += __shfl_xor(s, 1); s += __shfl_xor(s, 2);
                s += __shfl_xor(s, 4); s += __shfl_xor(s, 8);
                if (ml == 0) {
                    int nloc = (tile & 3)*128 + wv*32 + mt*16 + quad*4 + r;
                    score[((size_t)(b*KK + k))*NN + nloc] = s + kb;
                }
            }
        }
    }
}

// ---------------------------------------------------------------------------
// k2 fat: edge-sum (blocks 0..8191) || attctx (blocks 8192..8447)
// edge-sum: nl[i] = sum_s gelu(pvfb[aa[i,s]] + pet[edge[ba[i,s]]]) * nbm[i,s]
// one wave per output row; lane = (sgrp<4)*16 + colchunk
// ---------------------------------------------------------------------------
__global__ __launch_bounds__(256) void layer_k2(
    const short* __restrict__ pvfb, const float* __restrict__ pet,
    const int* __restrict__ aadj, const int* __restrict__ badj,
    const int* __restrict__ edge, const float* __restrict__ nbm,
    short* __restrict__ nlh, short* __restrict__ nll,
    const float* __restrict__ score, const float* __restrict__ vm,
    const float* __restrict__ vfc,
    float* __restrict__ satt, float* __restrict__ ctx)
{
    __shared__ float smem[768];
    const int bid = blockIdx.x;
    const int t = threadIdx.x;

    if (bid < 8192) {
        const int w = t >> 6, l = t & 63;
        const int i = bid*4 + w;            // output row < 32768
        const int sg = l >> 4, j = l & 15;  // s-group, col-chunk (8 cols)
        float acc[8];
        #pragma unroll
        for (int c = 0; c < 8; ++c) acc[c] = 0.f;
        #pragma unroll
        for (int it = 0; it < 2; ++it) {
            int s = it*4 + sg;
            int flat = i*8 + s;
            int g = aadj[flat];
            int eid = edge[badj[flat]];
            float nv = nbm[flat];
            bf16x8 pv8 = *(const bf16x8*)(pvfb + (size_t)g*128 + j*8);
            const float* pp = pet + (size_t)eid*128 + j*8;
            float4 p0 = *(const float4*)pp, p1 = *(const float4*)(pp+4);
            float pe[8] = {p0.x,p0.y,p0.z,p0.w,p1.x,p1.y,p1.z,p1.w};
            #pragma unroll
            for (int c = 0; c < 8; ++c)
                acc[c] += gelu1(bs2f(pv8[c]) + pe[c]) * nv;
        }
        #pragma unroll
        for (int c = 0; c < 8; ++c) {
            acc[c] += __shfl_xor(acc[c], 16);
            acc[c] += __shfl_xor(acc[c], 32);
        }
        if (sg == 0) {
            short hs[8], ls[8];
            #pragma unroll
            for (int c = 0; c < 8; ++c) split2(acc[c], hs[c], ls[c]);
            size_t o = (size_t)i*128 + j*8;
            *(short4*)(nlh + o)     = make_short4(hs[0],hs[1],hs[2],hs[3]);
            *(short4*)(nlh + o + 4) = make_short4(hs[4],hs[5],hs[6],hs[7]);
            *(short4*)(nll + o)     = make_short4(ls[0],ls[1],ls[2],ls[3]);
            *(short4*)(nll + o + 4) = make_short4(ls[4],ls[5],ls[6],ls[7]);
        }
    } else {
        // ---------------- attctx ----------------
        float* red = smem;        // 256
        float* att = smem + 256;  // 512
        const int bk = bid - 8192, b = bk >> 2;
        float v0 = score[(size_t)bk*NN + t], v1 = score[(size_t)bk*NN + 256 + t];
        red[t] = fmaxf(v0, v1); __syncthreads();
        for (int s = 128; s; s >>= 1) { if (t < s) red[t] = fmaxf(red[t], red[t+s]); __syncthreads(); }
        float mx = red[0]; __syncthreads();
        float e0 = expf(v0 - mx) * vm[b*NN + t];
        float e1 = expf(v1 - mx) * vm[b*NN + t + 256];
        red[t] = e0 + e1; __syncthreads();
        for (int s = 128; s; s >>= 1) { if (t < s) red[t] += red[t+s]; __syncthreads(); }
        float sum = red[0];
        float inv = 1.f / (sum + 1e-6f);
        att[t] = e0*inv; att[t+256] = e1*inv;
        if (t == 0) satt[bk] = sum*inv;
        __syncthreads();
        const int d = t & 127, h = t >> 7;
        float acc = 0.f;
        const float* V = vfc + (size_t)b*NN*HH;
        #pragma unroll 8
        for (int n = h*256; n < h*256 + 256; ++n) acc += att[n]*V[(size_t)n*HH + d];
        red[t] = acc; __syncthreads();
        if (t < 128) ctx[(size_t)bk*HH + t] = red[t] + red[t+128];
    }
}

// ---------------------------------------------------------------------------
// k3 fat: vchain (blocks 0..2047) || master_fused2 (blocks 2048..2111)
// ---------------------------------------------------------------------------
__global__ __launch_bounds__(256) void layer_k3(
    // vchain
    const short* __restrict__ nlh, const short* __restrict__ nll,
    const float* __restrict__ vfc, const short* __restrict__ vfch, const short* __restrict__ vfcl,
    float* __restrict__ vfn, short* __restrict__ vfnh, short* __restrict__ vfnl,
    const short* __restrict__ h0b,
    const short* __restrict__ wu2, const float* __restrict__ u2b,
    const short* __restrict__ wfu, const float* __restrict__ fub,
    const short* __restrict__ wzm, const float* __restrict__ zmb,
    const short* __restrict__ wih, const short* __restrict__ whh,
    const float* __restrict__ bih, const float* __restrict__ bhh,
    const float* __restrict__ t2, const float* __restrict__ m2m,
    float theta,
    // master
    const float* __restrict__ ctx, const float* __restrict__ satt,
    float* __restrict__ master,
    const float* __restrict__ wmain_w, const float* __restrict__ wmain_b,
    const float* __restrict__ khead_w, const float* __restrict__ khead_b,
    const float* __restrict__ wmaster_w, const float* __restrict__ wmaster_b,
    const float* __restrict__ wzs1_w,  const float* __restrict__ wzs1_b,
    const float* __restrict__ wzs2_w,  const float* __restrict__ wzs2_b,
    const float* __restrict__ WTih, const float* __restrict__ WThh,
    const float* __restrict__ bihm, const float* __restrict__ bhhm,
    const float* __restrict__ wm2m_n_w, const float* __restrict__ wm2m_n_b,
    const float* __restrict__ wzm2_n_w, const float* __restrict__ wzm2_n_b,
    float* __restrict__ m2m_out, float* __restrict__ t2_out)
{
    __shared__ __align__(16) float smemf[2688];
    const int bid = blockIdx.x;
    const int t = threadIdx.x;

    if (bid < 2048) {
        short* sh = (short*)smemf;
        short* sl = sh + 16*136;
        const int lane = t & 63, wv = t >> 6;
        const int quad = lane >> 4, ml = lane & 15;
        const int base = bid * 16;
        const int arow = base + ml;
        const int bb = base >> 9;
        const int c0 = wv*32 + ml;
        const int kq0 = quad*8;

        f32x4 acc0 = (f32x4){0.f,0.f,0.f,0.f}, acc1 = (f32x4){0.f,0.f,0.f,0.f};

        // stage A: hi = concat(nl, vf) @ u2
        #pragma unroll
        for (int kc = 0; kc < 8; ++kc) {
            const int kq = kc*32 + kq0;
            bf16x8 ah, al;
            if (kc < 4) {
                ah = *(const bf16x8*)(nlh + (size_t)arow*128 + kq);
                al = *(const bf16x8*)(nll + (size_t)arow*128 + kq);
            } else {
                ah = *(const bf16x8*)(vfch + (size_t)arow*128 + kq - 128);
                al = *(const bf16x8*)(vfcl + (size_t)arow*128 + kq - 128);
            }
            const short* bp0 = wu2 + (size_t)c0*256 + kq;
            const short* bp1 = wu2 + (size_t)(c0+16)*256 + kq;
            MFMA3(acc0, ah, al, *(const bf16x8*)bp0, *(const bf16x8*)(bp0+98304));
            MFMA3(acc1, ah, al, *(const bf16x8*)bp1, *(const bf16x8*)(bp1+98304));
        }
        f32x4 sup0, sup1;
        {
            float bj0 = u2b[c0], bj1 = u2b[c0+16];
            #pragma unroll
            for (int r = 0; r < 4; ++r) {
                int row = base + quad*4 + r;
                sup0[r] = 0.9f*(acc0[r] + bj0) + 0.1f*bs2f(h0b[(size_t)row*128 + c0]);
                sup1[r] = 0.9f*(acc1[r] + bj1) + 0.1f*bs2f(h0b[(size_t)row*128 + c0+16]);
            }
        }
        #pragma unroll
        for (int r = 0; r < 4; ++r) {
            int lrow = quad*4 + r;
            short h_, l_;
            split2(sup0[r], h_, l_); sh[lrow*136 + c0] = h_; sl[lrow*136 + c0] = l_;
            split2(sup1[r], h_, l_); sh[lrow*136 + c0+16] = h_; sl[lrow*136 + c0+16] = l_;
        }
        __syncthreads();

        // stage B: sv
        acc0 = (f32x4){0.f,0.f,0.f,0.f}; acc1 = (f32x4){0.f,0.f,0.f,0.f};
        #pragma unroll
        for (int kc = 0; kc < 4; ++kc) {
            const int kq = kc*32 + kq0;
            bf16x8 xh = *(const bf16x8*)&sh[ml*136 + kq];
            bf16x8 xl = *(const bf16x8*)&sl[ml*136 + kq];
            const short* bp0 = wfu + (size_t)c0*128 + kq;
            const short* bp1 = wfu + (size_t)(c0+16)*128 + kq;
            MFMA3(acc0, xh, xl, *(const bf16x8*)bp0, *(const bf16x8*)(bp0+49152));
            MFMA3(acc1, xh, xl, *(const bf16x8*)bp1, *(const bf16x8*)(bp1+49152));
        }
        f32x4 sv0, sv1;
        {
            float bj0 = fub[c0], bj1 = fub[c0+16];
            #pragma unroll
            for (int r = 0; r < 4; ++r) {
                sv0[r] = theta*(acc0[r] + bj0) + (1.f-theta)*sup0[r];
                sv1[r] = theta*(acc1[r] + bj1) + (1.f-theta)*sup1[r];
            }
        }
        __syncthreads();
        #pragma unroll
        for (int r = 0; r < 4; ++r) {
            int lrow = quad*4 + r;
            short h_, l_;
            split2(sv0[r], h_, l_); sh[lrow*136 + c0] = h_; sl[lrow*136 + c0] = l_;
            split2(sv1[r], h_, l_); sh[lrow*136 + c0+16] = h_; sl[lrow*136 + c0+16] = l_;
        }
        __syncthreads();

        // stage C: z-gate
        acc0 = (f32x4){0.f,0.f,0.f,0.f}; acc1 = (f32x4){0.f,0.f,0.f,0.f};
        #pragma unroll
        for (int kc = 0; kc < 4; ++kc) {
            const int kq = kc*32 + kq0;
            bf16x8 xh = *(const bf16x8*)&sh[ml*136 + kq];
            bf16x8 xl = *(const bf16x8*)&sl[ml*136 + kq];
            const short* bp0 = wzm + (size_t)c0*128 + kq;
            const short* bp1 = wzm + (size_t)(c0+16)*128 + kq;
            MFMA3(acc0, xh, xl, *(const bf16x8*)bp0, *(const bf16x8*)(bp0+49152));
            MFMA3(acc1, xh, xl, *(const bf16x8*)bp1, *(const bf16x8*)(bp1+49152));
        }
        f32x4 hid0, hid1;
        {
            float bj0 = zmb[c0], bj1 = zmb[c0+16];
            float t20 = t2[(size_t)bb*128 + c0], t21 = t2[(size_t)bb*128 + c0+16];
            float m20 = m2m[(size_t)bb*128 + c0], m21 = m2m[(size_t)bb*128 + c0+16];
            #pragma unroll
            for (int r = 0; r < 4; ++r) {
                float z0 = sig1(acc0[r] + bj0 + t20);
                float z1 = sig1(acc1[r] + bj1 + t21);
                hid0[r] = (1.f-z0)*sv0[r] + z0*m20;
                hid1[r] = (1.f-z1)*sv1[r] + z1*m21;
            }
        }
        __syncthreads();
        #pragma unroll
        for (int r = 0; r < 4; ++r) {
            int lrow = quad*4 + r;
            short h_, l_;
            split2(hid0[r], h_, l_); sh[lrow*136 + c0] = h_; sl[lrow*136 + c0] = l_;
            split2(hid1[r], h_, l_); sh[lrow*136 + c0+16] = h_; sl[lrow*136 + c0+16] = l_;
        }
        __syncthreads();

        // stage D: GRU
        bf16x8 xfh[4], xfl[4], vh_[4], vl_[4];
        #pragma unroll
        for (int kc = 0; kc < 4; ++kc) {
            const int kq = kc*32 + kq0;
            xfh[kc] = *(const bf16x8*)&sh[ml*136 + kq];
            xfl[kc] = *(const bf16x8*)&sl[ml*136 + kq];
            vh_[kc] = *(const bf16x8*)(vfch + (size_t)arow*128 + kq);
            vl_[kc] = *(const bf16x8*)(vfcl + (size_t)arow*128 + kq);
        }
        f32x4 rg0, rg1, zg0, zg1;
        #pragma unroll
        for (int g = 0; g < 3; ++g) {
            f32x4 gi0 = (f32x4){0.f,0.f,0.f,0.f}, gi1 = (f32x4){0.f,0.f,0.f,0.f};
            f32x4 gh0 = (f32x4){0.f,0.f,0.f,0.f}, gh1 = (f32x4){0.f,0.f,0.f,0.f};
            #pragma unroll
            for (int kc = 0; kc < 4; ++kc) {
                const int kq = kc*32 + kq0;
                const size_t w0 = (size_t)(g*128 + c0)*128 + kq;
                const size_t w1 = (size_t)(g*128 + c0+16)*128 + kq;
                MFMA3(gi0, xfh[kc], xfl[kc], *(const bf16x8*)(wih+w0), *(const bf16x8*)(wih+w0+49152));
                MFMA3(gi1, xfh[kc], xfl[kc], *(const bf16x8*)(wih+w1), *(const bf16x8*)(wih+w1+49152));
                MFMA3(gh0, vh_[kc], vl_[kc], *(const bf16x8*)(whh+w0), *(const bf16x8*)(whh+w0+49152));
                MFMA3(gh1, vh_[kc], vl_[kc], *(const bf16x8*)(whh+w1), *(const bf16x8*)(whh+w1+49152));
            }
            if (g == 0) {
                float b10 = bih[c0], b20 = bhh[c0], b11 = bih[c0+16], b21 = bhh[c0+16];
                #pragma unroll
                for (int r = 0; r < 4; ++r) {
                    rg0[r] = sig1(gi0[r] + b10 + gh0[r] + b20);
                    rg1[r] = sig1(gi1[r] + b11 + gh1[r] + b21);
                }
            } else if (g == 1) {
                float b10 = bih[128+c0], b20 = bhh[128+c0], b11 = bih[128+c0+16], b21 = bhh[128+c0+16];
                #pragma unroll
                for (int r = 0; r < 4; ++r) {
                    zg0[r] = sig1(gi0[r] + b10 + gh0[r] + b20);
                    zg1[r] = sig1(gi1[r] + b11 + gh1[r] + b21);
                }
            } else {
                float b10 = bih[256+c0], b20 = bhh[256+c0], b11 = bih[256+c0+16], b21 = bhh[256+c0+16];
                #pragma unroll
                for (int r = 0; r < 4; ++r) {
                    int row = base + quad*4 + r;
                    size_t off0 = (size_t)row*128 + c0;
                    size_t off1 = off0 + 16;
                    float n0 = tanhf(gi0[r] + b10 + rg0[r]*(gh0[r] + b20));
                    float n1 = tanhf(gi1[r] + b11 + rg1[r]*(gh1[r] + b21));
                    float o0 = (1.f-zg0[r])*n0 + zg0[r]*vfc[off0];
                    float o1 = (1.f-zg1[r])*n1 + zg1[r]*vfc[off1];
                    vfn[off0] = o0; vfn[off1] = o1;
                    short h_, l_;
                    split2(o0, h_, l_); vfnh[off0] = h_; vfnl[off0] = l_;
                    split2(o1, h_, l_); vfnh[off1] = h_; vfnl[off1] = l_;
                }
            }
        }
    } else {
        // ---------------- master path ----------------
        float* xs = smemf;            // 512
        float* ms = smemf + 512;      // 128
        float* msN = smemf + 640;     // 128
        float* v_mtm = smemf + 768;   // 128
        float* v_mself = smemf + 896; // 128
        float* v_m2m = smemf + 1024;  // 128
        float* v_t2 = smemf + 1152;   // 128
        float* v_ts1 = smemf + 1280;  // 128
        float* v_ts2 = smemf + 1408;  // 128
        float* v_hsup = smemf + 1536; // 128
        float* gi = smemf + 1664;     // 384
        float* gh2 = smemf + 2048;    // 384
        float* red = smemf + 2432;    // 256
        const int b = bid - 2048;

        if (t < 128) ms[t] = master[(size_t)b*128 + t];
        __syncthreads();

        const int c = t & 127, p = t >> 7;

        #pragma unroll
        for (int k = 0; k < 4; ++k) {
            const float* cx = ctx + ((size_t)b*KK + k)*128;
            const float* Wk = wmain_w + (size_t)k*16384;
            float s = 0.f;
            for (int d = p*64; d < p*64+64; ++d) s += cx[d]*Wk[(size_t)d*128 + c];
            red[t] = s; __syncthreads();
            if (t < 128) xs[k*128 + c] = red[c] + red[c+128] + satt[(size_t)b*KK + k]*wmain_b[k*128 + c];
            __syncthreads();
        }

        auto matvec = [&](const float* src, const float* __restrict__ W,
                          const float* __restrict__ bias, int K, float* out, int act) {
            int half = K >> 1;
            int k0 = p*half, k1 = k0 + half;
            float s = 0.f;
            for (int k = k0; k < k1; ++k) s += src[k]*W[(size_t)k*128 + c];
            red[t] = s; __syncthreads();
            if (t < 128) {
                float v = red[c] + red[c+128] + bias[c];
                if (act == 1) v = gelu1(v); else if (act == 2) v = tanhf(v);
                out[c] = v;
            }
            __syncthreads();
        };

        matvec(xs, khead_w, khead_b, 512, v_mtm, 2);
        matvec(ms, wmaster_w, wmaster_b, 128, v_mself, 1);
        matvec(v_mself, wzs1_w, wzs1_b, 128, v_ts1, 0);
        matvec(v_mtm, wzs2_w, wzs2_b, 128, v_ts2, 0);

        if (t < 128) {
            float z = sig1(v_ts1[t] + v_ts2[t]);
            v_hsup[t] = (1.f-z)*v_mself[t] + z*v_mtm[t];
        }
        __syncthreads();

        for (int j = t; j < 384; j += 256) {
            float a = 0.f, h2 = 0.f;
            for (int k = 0; k < 128; ++k) {
                a  += v_hsup[k]*WTih[(size_t)k*384 + j];
                h2 += ms[k]*WThh[(size_t)k*384 + j];
            }
            gi[j] = a + bihm[j];
            gh2[j] = h2 + bhhm[j];
        }
        __syncthreads();
        if (t < 128) {
            float r = sig1(gi[t] + gh2[t]);
            float z = sig1(gi[128+t] + gh2[128+t]);
            float n = tanhf(gi[256+t] + r*gh2[256+t]);
            float nm = (1.f-z)*n + z*ms[t];
            master[(size_t)b*128 + t] = nm;
            msN[t] = nm;
        }
        __syncthreads();

        matvec(msN, wm2m_n_w, wm2m_n_b, 128, v_m2m, 1);
        matvec(v_m2m, wzm2_n_w, wzm2_n_b, 128, v_t2, 0);
        if (t < 128) {
            m2m_out[(size_t)b*128 + t] = v_m2m[t];
            t2_out[(size_t)b*128 + t]  = v_t2[t];
        }
    }
}

// ---------------------------------------------------------------------------
// embed: vf = gelu((atomf[vertex]*vm)@emb + b); stores fp32 vf, planes, bf16 h0
// ---------------------------------------------------------------------------
__global__ __launch_bounds__(256) void embed_kernel(
    const float* __restrict__ atomf, const int* __restrict__ vertex,
    const float* __restrict__ vmask,
    const short* __restrict__ WT, const float* __restrict__ bias,
    float* __restrict__ vf, short* __restrict__ h0b,
    short* __restrict__ vfh, short* __restrict__ vfl)
{
    const int t = threadIdx.x;
    const int lane = t & 63, wv = t >> 6;
    const int quad = lane >> 4, ml = lane & 15;
    const int m0 = blockIdx.x*128 + wv*32;
    const int r0 = m0 + ml, r1 = m0 + 16 + ml;
    const int ga0 = vertex[r0], ga1 = vertex[r1];
    const float vm0 = vmask[r0], vm1 = vmask[r1];

    f32x4 acc[16];
    #pragma unroll
    for (int i = 0; i < 16; ++i) acc[i] = (f32x4){0.f,0.f,0.f,0.f};
    const short* wcol = WT + (size_t)ml*96;

    #pragma unroll
    for (int kc = 0; kc < 3; ++kc) {
        const int kq = kc*32 + quad*8;
        float av0[8], av1[8];
        const float* p0r = atomf + (size_t)ga0*AF + kq;
        const float* p1r = atomf + (size_t)ga1*AF + kq;
        #pragma unroll
        for (int j2 = 0; j2 < 4; ++j2) {
            int k = kq + 2*j2;
            if (k + 2 <= AF) {
                float2 v0 = *(const float2*)(p0r + 2*j2);
                float2 v1 = *(const float2*)(p1r + 2*j2);
                av0[2*j2]=v0.x*vm0; av0[2*j2+1]=v0.y*vm0;
                av1[2*j2]=v1.x*vm1; av1[2*j2+1]=v1.y*vm1;
            } else { av0[2*j2]=0.f; av0[2*j2+1]=0.f; av1[2*j2]=0.f; av1[2*j2+1]=0.f; }
        }
        bf16x8 a0h, a0l, a1h, a1l;
        #pragma unroll
        for (int j = 0; j < 8; ++j) {
            short h, l;
            split2(av0[j], h, l); a0h[j]=h; a0l[j]=l;
            split2(av1[j], h, l); a1h[j]=h; a1l[j]=l;
        }
        #pragma unroll
        for (int nt = 0; nt < 8; ++nt) {
            const short* bp = wcol + (size_t)nt*16*96 + kq;
            bf16x8 bh = *(const bf16x8*)bp;
            bf16x8 bl = *(const bf16x8*)(bp + 12288);
            MFMA3(acc[nt],   a0h, a0l, bh, bl);
            MFMA3(acc[8+nt], a1h, a1l, bh, bl);
        }
    }

    #pragma unroll
    for (int mt = 0; mt < 2; ++mt) {
        #pragma unroll
        for (int nt = 0; nt < 8; ++nt) {
            int col = nt*16 + ml;
            float bj = bias[col];
            #pragma unroll
            for (int r = 0; r < 4; ++r) {
                int gm = m0 + mt*16 + quad*4 + r;
                float v = gelu1(acc[mt*8+nt][r] + bj);
                size_t off = (size_t)gm*128 + col;
                vf[off] = v;
                short h_, l_; split2(v, h_, l_);
                vfh[off] = h_; vfl[off] = l_;
                h0b[off] = h_;
            }
        }
    }
}

// ---------------------------------------------------------------------------
// master_init2: master = sum(vf*vm); m2m_0/t2_0
// ---------------------------------------------------------------------------
__global__ __launch_bounds__(256) void master_init2(
    const float* __restrict__ vf, const float* __restrict__ vm,
    const float* __restrict__ wm2m_w, const float* __restrict__ wm2m_b,
    const float* __restrict__ wzm2_w, const float* __restrict__ wzm2_b,
    float* __restrict__ master, float* __restrict__ m2m_out, float* __restrict__ t2_out)
{
    __shared__ float red[256], ms[128], v_m2m[128];
    const int b = blockIdx.x, t = threadIdx.x;
    const int hcol = t & 127, half = t >> 7;
    float s = 0.f;
    for (int n = half; n < NN; n += 2)
        s += vf[((size_t)b*NN + n)*HH + hcol] * vm[b*NN + n];
    red[t] = s; __syncthreads();
    if (half == 0) { float v = red[hcol] + red[hcol+128]; ms[hcol] = v; master[(size_t)b*HH + hcol] = v; }
    __syncthreads();
    const int c = t & 127, p = t >> 7;
    {
        float s2 = 0.f;
        for (int k = p*64; k < p*64+64; ++k) s2 += ms[k]*wm2m_w[(size_t)k*128 + c];
        red[t] = s2; __syncthreads();
        if (t < 128) { float v = gelu1(red[c] + red[c+128] + wm2m_b[c]); v_m2m[c] = v; m2m_out[(size_t)b*128 + c] = v; }
        __syncthreads();
    }
    {
        float s2 = 0.f;
        for (int k = p*64; k < p*64+64; ++k) s2 += v_m2m[k]*wzm2_w[(size_t)k*128 + c];
        red[t] = s2; __syncthreads();
        if (t < 128) t2_out[(size_t)b*128 + c] = red[c] + red[c+128] + wzm2_b[c];
    }
}

// ---------------------------------------------------------------------------
// weight prep: all converts/transposes + pet table
// ---------------------------------------------------------------------------
__device__ __forceinline__ void cvt_t2(const float* __restrict__ src, short* __restrict__ dst,
                                       int i, int K, int Kpad, int total, int zrows)
{
    int z = i / (128*Kpad); int rem = i - z*128*Kpad;
    int col = rem / Kpad; int k = rem - col*Kpad;
    float v = (k < K) ? src[(size_t)z*zrows*128 + (size_t)k*128 + col] : 0.f;
    short h, l; split2(v, h, l);
    dst[i] = h; dst[total + i] = l;
}

__global__ void wprep_kernel(
    const float* __restrict__ emb_w, const float* __restrict__ wvm_w,
    const float* __restrict__ u1_w, const float* __restrict__ u1_b,
    const float* __restrict__ u2_w,
    const float* __restrict__ fu_w, const float* __restrict__ wzm1_w,
    const float* __restrict__ g_wih, const float* __restrict__ g_whh,
    const float* __restrict__ gm_wih, const float* __restrict__ gm_whh,
    const float* __restrict__ bondf,
    short* __restrict__ wt_emb, short* __restrict__ wt_wvm,
    short* __restrict__ wt_pv, short* __restrict__ wt_u2,
    short* __restrict__ wt_fu, short* __restrict__ wt_wzm1,
    short* __restrict__ wt_gih, short* __restrict__ wt_ghh,
    float* __restrict__ WTih_s, float* __restrict__ WThh_s,
    float* __restrict__ pet)
{
    int i = blockIdx.x*256 + threadIdx.x;
    if (i < 12288) cvt_t2(emb_w, wt_emb, i, 82, 96, 12288, 82);
    else if (i < 208896) cvt_t2(wvm_w, wt_wvm, i-12288, 128, 128, 196608, 128);
    else if (i < 258048) cvt_t2(u1_w, wt_pv, i-208896, 128, 128, 49152, 134);
    else if (i < 356352) cvt_t2(u2_w, wt_u2, i-258048, 256, 256, 98304, 256);
    else if (i < 405504) cvt_t2(fu_w, wt_fu, i-356352, 128, 128, 49152, 128);
    else if (i < 454656) cvt_t2(wzm1_w, wt_wzm1, i-405504, 128, 128, 49152, 128);
    else if (i < 503808) { int j = i-454656; short h,l; split2(g_wih[j],h,l); wt_gih[j]=h; wt_gih[49152+j]=l; }
    else if (i < 552960) { int j = i-503808; short h,l; split2(g_whh[j],h,l); wt_ghh[j]=h; wt_ghh[49152+j]=l; }
    else if (i < 602112) { int o = i-552960; int k = o/384, j = o-k*384; WTih_s[o] = gm_wih[j*128 + k]; }
    else if (i < 651264) { int o = i-602112; int k = o/384, j = o-k*384; WThh_s[o] = gm_whh[j*128 + k]; }
    else if (i < 655104) {
        int o = i-651264;               // < 3*10*128
        int l = o / 1280; int rem = o - l*1280;
        int e = rem >> 7; int c = rem & 127;
        float acc = u1_b[l*128 + c];
        #pragma unroll
        for (int j = 0; j < 6; ++j)
            acc += bondf[e*6 + j] * u1_w[((size_t)l*134 + 128 + j)*128 + c];
        pet[o] = acc;
    }
}

__global__ void copy_out_kernel(const float* __restrict__ vf, const float* __restrict__ master,
                                float* __restrict__ out)
{
    int i = blockIdx.x*256 + threadIdx.x;
    const int nvf4 = SLAB/4;
    if (i < nvf4) ((float4*)out)[i] = ((const float4*)vf)[i];
    else ((float4*)out)[i] = ((const float4*)master)[i - nvf4];
}

// ---------------------------------------------------------------------------
extern "C" void kernel_launch(void* const* d_in, const int* in_sizes, int n_in,
                              void* d_out, int out_size, void* d_ws, size_t ws_size,
                              hipStream_t stream)
{
    (void)in_sizes; (void)n_in; (void)out_size; (void)ws_size;
    const float* vmask = (const float*)d_in[1];
    const int*   vertex= (const int*)d_in[2];
    const int*   edge  = (const int*)d_in[3];
    const int*   aadj  = (const int*)d_in[4];
    const int*   badj  = (const int*)d_in[5];
    const float* nbm   = (const float*)d_in[6];
    const float* atomf = (const float*)d_in[7];
    const float* bondf = (const float*)d_in[8];
    const float* emb_w = (const float*)d_in[9];
    const float* emb_b = (const float*)d_in[10];
    const float* u1_w  = (const float*)d_in[11];
    const float* u1_b  = (const float*)d_in[12];
    const float* u2_w  = (const float*)d_in[13];
    const float* u2_b  = (const float*)d_in[14];
    const float* fu_w  = (const float*)d_in[15];
    const float* fu_b  = (const float*)d_in[16];
    const float* wvm_w = (const float*)d_in[17];
    const float* wvm_b = (const float*)d_in[18];
    const float* wmain_w=(const float*)d_in[19];
    const float* wmain_b=(const float*)d_in[20];
    const float* wbmm_w= (const float*)d_in[21];
    const float* wbmm_b= (const float*)d_in[22];
    const float* khead_w=(const float*)d_in[23];
    const float* khead_b=(const float*)d_in[24];
    const float* wmaster_w=(const float*)d_in[25];
    const float* wmaster_b=(const float*)d_in[26];
    const float* wm2m_w= (const float*)d_in[27];
    const float* wm2m_b= (const float*)d_in[28];
    const float* wzm1_w= (const float*)d_in[29];
    const float* wzm1_b= (const float*)d_in[30];
    const float* wzm2_w= (const float*)d_in[31];
    const float* wzm2_b= (const float*)d_in[32];
    const float* wzs1_w= (const float*)d_in[33];
    const float* wzs1_b= (const float*)d_in[34];
    const float* wzs2_w= (const float*)d_in[35];
    const float* wzs2_b= (const float*)d_in[36];
    const float* g_wih = (const float*)d_in[37];
    const float* g_whh = (const float*)d_in[38];
    const float* g_bih = (const float*)d_in[39];
    const float* g_bhh = (const float*)d_in[40];
    const float* gm_wih= (const float*)d_in[41];
    const float* gm_whh= (const float*)d_in[42];
    const float* gm_bih= (const float*)d_in[43];
    const float* gm_bhh= (const float*)d_in[44];

    float* ws     = (float*)d_ws;
    float* vfA    = ws;
    float* vfB    = vfA + SLAB;
    float* score  = vfB + SLAB;
    float* ctx    = score + BB*KK*NN;
    float* satt   = ctx + BB*KK*HH;
    float* master = satt + BB*KK;
    float* m2m    = master + BB*HH;
    float* t2     = m2m + BB*HH;
    float* WTih_s = t2 + BB*HH;
    float* WThh_s = WTih_s + 128*384;
    float* pet    = WThh_s + 128*384;       // 3*10*128
    short* vfhA   = (short*)(pet + 3840);
    short* vflA   = vfhA + SLAB;
    short* vfhB   = vflA + SLAB;
    short* vflB   = vfhB + SLAB;
    short* nlh    = vflB + SLAB;
    short* nll    = nlh + SLAB;
    short* pvfb   = nll + SLAB;
    short* h0b    = pvfb + SLAB;
    short* wt_emb   = h0b + SLAB;
    short* wt_wvm   = wt_emb   + 2*12288;
    short* wt_pv    = wt_wvm   + 2*196608;
    short* wt_u2    = wt_pv    + 2*49152;
    short* wt_fu    = wt_u2    + 2*98304;
    short* wt_wzm1  = wt_fu    + 2*49152;
    short* wt_gih   = wt_wzm1  + 2*49152;
    short* wt_ghh   = wt_gih   + 2*49152;

    wprep_kernel<<<2560, 256, 0, stream>>>(
        emb_w, wvm_w, u1_w, u1_b, u2_w, fu_w, wzm1_w, g_wih, g_whh, gm_wih, gm_whh,
        bondf,
        wt_emb, wt_wvm, wt_pv, wt_u2, wt_fu, wt_wzm1, wt_gih, wt_ghh,
        WTih_s, WThh_s, pet);

    embed_kernel<<<256, 256, 0, stream>>>(atomf, vertex, vmask, wt_emb, emb_b,
                                          vfA, h0b, vfhA, vflA);

    master_init2<<<BB, 256, 0, stream>>>(vfA, vmask, wm2m_w, wm2m_b, wzm2_w, wzm2_b,
                                         master, m2m, t2);

    for (int i = 0; i < LL; ++i) {
        float theta = logf(0.5f/(float)(i+1) + 1.f);
        const bool even = (i % 2 == 0);
        float* vfc  = even ? vfA  : vfB;
        short* vfch = even ? vfhA : vfhB;
        short* vfcl = even ? vflA : vflB;
        float* vfn  = even ? vfB  : vfA;
        short* vfnh = even ? vfhB : vfhA;
        short* vfnl = even ? vflB : vflA;
        int nx = (i+1 < LL) ? i+1 : i;

        layer_k1<<<1280, 256, 0, stream>>>(
            vfch, vfcl,
            wt_pv + (size_t)i*16384, pvfb,
            wt_wvm + (size_t)i*4*16384, wvm_b + (size_t)i*4*128,
            master, wbmm_w + (size_t)i*KK*HH, wbmm_b + (size_t)i*KK, score);

        layer_k2<<<8448, 256, 0, stream>>>(
            pvfb, pet + (size_t)i*1280,
            aadj, badj, edge, nbm, nlh, nll,
            score, vmask, vfc, satt, ctx);

        layer_k3<<<2112, 256, 0, stream>>>(
            nlh, nll, vfc, vfch, vfcl, vfn, vfnh, vfnl, h0b,
            wt_u2 + (size_t)i*128*256, u2_b + i*HH,
            wt_fu + (size_t)i*16384, fu_b + i*HH,
            wt_wzm1 + (size_t)i*16384, wzm1_b + i*HH,
            wt_gih, wt_ghh, g_bih, g_bhh,
            t2, m2m, theta,
            ctx, satt, master,
            wmain_w + (size_t)i*KK*HH*HH, wmain_b + (size_t)i*KK*HH,
            khead_w + (size_t)i*KK*HH*HH, khead_b + i*HH,
            wmaster_w + (size_t)i*HH*HH, wmaster_b + i*HH,
            wzs1_w + (size_t)i*HH*HH, wzs1_b + i*HH,
            wzs2_w + (size_t)i*HH*HH, wzs2_b + i*HH,
            WTih_s, WThh_s, gm_bih, gm_bhh,
            wm2m_w + (size_t)nx*HH*HH, wm2m_b + nx*HH,
            wzm2_w + (size_t)nx*HH*HH, wzm2_b + nx*HH,
            m2m, t2);
    }

    copy_out_kernel<<<(SLAB + BB*HH)/4/256, 256, 0, stream>>>(vfB, master, (float*)d_out);
}